// Round 13
// baseline (832.934 us; speedup 1.0000x reference)
//
#include <hip/hip_runtime.h>

#define BN_EPS 1e-5f
#define MFMA_B16(a, b, c) __builtin_amdgcn_mfma_f32_16x16x32_bf16((a), (b), (c), 0, 0, 0)

typedef short s16x8 __attribute__((ext_vector_type(8)));
typedef float f32x4v __attribute__((ext_vector_type(4)));

__device__ __forceinline__ unsigned fenc(float f) {
    unsigned u = __float_as_uint(f);
    return (u & 0x80000000u) ? ~u : (u | 0x80000000u);
}
__device__ __forceinline__ float fdec(unsigned e) {
    unsigned u = (e & 0x80000000u) ? (e ^ 0x80000000u) : ~e;
    return __uint_as_float(u);
}
__device__ __forceinline__ unsigned short f2b(float f) {
    unsigned u = __float_as_uint(f);
    unsigned r = u + 0x7FFFu + ((u >> 16) & 1u);
    return (unsigned short)(r >> 16);
}
__device__ __forceinline__ float b2f(unsigned short h) {
    return __uint_as_float(((unsigned)h) << 16);
}

// argmax combine with first-max (lowest index) tie-break
__device__ __forceinline__ void cmb(float& v, int& i, float ov, int oi) {
    bool t = (ov > v) || ((ov == v) && (oi < i));
    v = t ? ov : v;
    i = t ? oi : i;
}
// same, carrying winner coords
__device__ __forceinline__ void cmb5(float& v, int& i, float& x, float& y, float& z,
                                     float ov, int oi, float ox, float oy, float oz) {
    bool t = (ov > v) || ((ov == v) && (oi < i));
    v = t ? ov : v; i = t ? oi : i;
    x = t ? ox : x; y = t ? oy : y; z = t ? oz : z;
}
template<int CTRL>
__device__ __forceinline__ float dppf(float x) {
    return __uint_as_float((unsigned)__builtin_amdgcn_update_dpp(
        0, (int)__float_as_uint(x), CTRL, 0xF, 0xF, true));
}
template<int CTRL>
__device__ __forceinline__ int dppi(int x) {
    return __builtin_amdgcn_update_dpp(0, x, CTRL, 0xF, 0xF, true);
}

// ---------- build concatenated xyz (B,1280,3) ----------
__global__ __launch_bounds__(256) void build_xyz_kernel(
    const float* __restrict__ pc, const float* __restrict__ gpc, float* __restrict__ xyz)
{
    int p = blockIdx.x * 256 + threadIdx.x;
    if (p >= 64 * 1280) return;
    int b = p / 1280, i = p % 1280;
    const float* src = (i < 1024) ? (pc + ((size_t)b * 1024 + i) * 3)
                                  : (gpc + ((size_t)b * 256 + (i - 1024)) * 3);
    xyz[(size_t)p * 3 + 0] = src[0];
    xyz[(size_t)p * 3 + 1] = src[1];
    xyz[(size_t)p * 3 + 2] = src[2];
}

// ---------- prep: transpose SA1+SA2 weights to split-bf16 W^T[n][k] (hi+lo) ----------
__global__ __launch_bounds__(256) void prep_w_kernel(
    const float* __restrict__ w2a, const float* __restrict__ w2b, const float* __restrict__ w2c,
    const float* __restrict__ w1a, const float* __restrict__ w1b, const float* __restrict__ w1c,
    unsigned short* __restrict__ W1Th, unsigned short* __restrict__ W1Tl,
    unsigned short* __restrict__ W2Th, unsigned short* __restrict__ W2Tl,
    unsigned short* __restrict__ W3Th, unsigned short* __restrict__ W3Tl,
    unsigned short* __restrict__ A1Th, unsigned short* __restrict__ A1Tl,
    unsigned short* __restrict__ B1Th, unsigned short* __restrict__ B1Tl,
    unsigned short* __restrict__ C1Th, unsigned short* __restrict__ C1Tl)
{
    int i = blockIdx.x * 256 + threadIdx.x;
    float v = 0.f;
    unsigned short* dh; unsigned short* dl; int j;
    if (i < 20480) {                       // SA2 W1T 128 x 160
        int n = i / 160, k = i % 160;
        if (k < 128)       v = w2a[(size_t)(3 + k) * 128 + n];
        else if (k < 131)  v = w2a[(size_t)(k - 128) * 128 + n];
        dh = W1Th; dl = W1Tl; j = i;
    } else if (i < 36864) {                // SA2 W2T 128 x 128
        j = i - 20480;
        int n = j / 128, k = j % 128;
        v = w2b[(size_t)k * 128 + n];
        dh = W2Th; dl = W2Tl;
    } else if (i < 69632) {                // SA2 W3T 256 x 128
        j = i - 36864;
        int n = j / 128, k = j % 128;
        v = w2c[(size_t)k * 256 + n];
        dh = W3Th; dl = W3Tl;
    } else if (i < 71680) {                // SA1 A1T 64 x 32
        j = i - 69632;
        int n = j / 32, k = j % 32;
        if (k < 7) v = w1a[(size_t)k * 64 + n];
        dh = A1Th; dl = A1Tl;
    } else if (i < 75776) {                // SA1 B1T 64 x 64
        j = i - 71680;
        int n = j / 64, k = j % 64;
        v = w1b[(size_t)k * 64 + n];
        dh = B1Th; dl = B1Tl;
    } else if (i < 83968) {                // SA1 C1T 128 x 64
        j = i - 75776;
        int n = j / 64, k = j % 64;
        v = w1c[(size_t)k * 128 + n];
        dh = C1Th; dl = C1Tl;
    } else return;
    unsigned short hi = f2b(v);
    unsigned short lo = f2b(v - b2f(hi));
    dh[j] = hi; dl[j] = lo;
}

// ---------- reduce per-block stat partials (row-split, atomic accumulate) ----------
__global__ __launch_bounds__(256) void reduce_stats_kernel(
    const float* __restrict__ PS, const float* __restrict__ PQ,
    int nblk, int C, float* __restrict__ osum, float* __restrict__ osq)
{
    __shared__ float rs_[256], rq_[256];
    int c = blockIdx.x, t = threadIdx.x;
    int L = nblk / gridDim.y;
    int r0 = blockIdx.y * L;
    float s = 0.f, q = 0.f;
    for (int i = r0 + t; i < r0 + L; i += 256) {
        s += PS[(size_t)i * C + c];
        q += PQ[(size_t)i * C + c];
    }
    rs_[t] = s; rq_[t] = q;
    __syncthreads();
    for (int off = 128; off >= 1; off >>= 1) {
        if (t < off) { rs_[t] += rs_[t + off]; rq_[t] += rq_[t + off]; }
        __syncthreads();
    }
    if (t == 0) { atomicAdd(&osum[c], rs_[0]); atomicAdd(&osq[c], rq_[0]); }
}

// ---------- FPS multi-wave: 4 waves/batch, P points/thread, SoA LDS ----------
// SoA coord planes -> contiguous per-thread reloads (wide, pipelined);
// candidate-coord prefetch + coord-carrying fold removes dependent broadcast.
template<int P>
__global__ __launch_bounds__(256, 1) void fps_mw_kernel(
    const float* __restrict__ xyz, int N, int S, int* __restrict__ oidx)
{
    __shared__ float sxx[1280], sxy[1280], sxz[1280];
    __shared__ float rv[2][4];
    __shared__ int   ri[2][4];
    int b = blockIdx.x, t = threadIdx.x;
    int wv = t >> 6, lane = t & 63;
    for (int i = t; i < N; i += 256) {
        const float* p = xyz + ((size_t)b * N + i) * 3;
        sxx[i] = p[0]; sxy[i] = p[1]; sxz[i] = p[2];
    }
    __syncthreads();
    float px[P], py[P], pz[P], dm[P];
    #pragma unroll
    for (int p = 0; p < P; p++) {
        int i = t * P + p;
        px[p] = sxx[i]; py[p] = sxy[i]; pz[p] = sxz[i];
        dm[p] = 1e10f;
    }
    int last = 0;
    float lx = sxx[0], ly = sxy[0], lz = sxz[0];
    for (int j = 0; j < S; j++) {
        if (t == 0) oidx[b * S + j] = last;
        float bv0 = -1.f, bv1 = -1.f; int bi0 = 0, bi1 = 0;
        #pragma unroll
        for (int p = 0; p < P; p++) {
            float dx = px[p] - lx, dy = py[p] - ly, dz = pz[p] - lz;
            float d2 = __fadd_rn(__fadd_rn(__fmul_rn(dx, dx), __fmul_rn(dy, dy)), __fmul_rn(dz, dz));
            float d = fminf(dm[p], d2); dm[p] = d;
            if (p & 1) { if (d > bv1) { bv1 = d; bi1 = t * P + p; } }
            else       { if (d > bv0) { bv0 = d; bi0 = t * P + p; } }
        }
        float bestv = bv0; int besti = bi0;
        cmb(bestv, besti, bv1, bi1);
        // full 64-lane reduce in DPP; valid result in lane 63
        cmb(bestv, besti, dppf<0xB1>(bestv),  dppi<0xB1>(besti));   // quad_perm [1,0,3,2]
        cmb(bestv, besti, dppf<0x4E>(bestv),  dppi<0x4E>(besti));   // quad_perm [2,3,0,1]
        cmb(bestv, besti, dppf<0x141>(bestv), dppi<0x141>(besti));  // row_half_mirror
        cmb(bestv, besti, dppf<0x140>(bestv), dppi<0x140>(besti));  // row_mirror
        cmb(bestv, besti, dppf<0x142>(bestv), dppi<0x142>(besti));  // row_bcast15
        cmb(bestv, besti, dppf<0x143>(bestv), dppi<0x143>(besti));  // row_bcast31
        int wbi = __builtin_amdgcn_readlane(besti, 63);
        unsigned wbu = (unsigned)__builtin_amdgcn_readlane((int)__float_as_uint(bestv), 63);
        int buf = j & 1;
        if (lane == 0) { rv[buf][wv] = __uint_as_float(wbu); ri[buf][wv] = wbi; }
        __syncthreads();
        // fetch 4 candidates (values, indices, coords) — loads independent, pipeline
        int   i0 = ri[buf][0], i1 = ri[buf][1], i2 = ri[buf][2], i3 = ri[buf][3];
        float v0 = rv[buf][0], v1 = rv[buf][1], v2 = rv[buf][2], v3 = rv[buf][3];
        float x0 = sxx[i0], y0 = sxy[i0], z0 = sxz[i0];
        float x1 = sxx[i1], y1 = sxy[i1], z1 = sxz[i1];
        float x2 = sxx[i2], y2 = sxy[i2], z2 = sxz[i2];
        float x3 = sxx[i3], y3 = sxy[i3], z3 = sxz[i3];
        cmb5(v0, i0, x0, y0, z0, v1, i1, x1, y1, z1);
        cmb5(v2, i2, x2, y2, z2, v3, i3, x3, y3, z3);
        cmb5(v0, i0, x0, y0, z0, v2, i2, x2, y2, z2);
        last = i0;
        lx = x0; ly = y0; lz = z0;
    }
}

// ---------- FPS single-wave (small N): SoA + DPP reduce + readlane ----------
template<int P>
__global__ __launch_bounds__(64, 1) void fps_wave_kernel(
    const float* __restrict__ xyz, int N, int S, int* __restrict__ oidx)
{
    __shared__ float sxx[128], sxy[128], sxz[128];
    int b = blockIdx.x, lane = threadIdx.x;
    for (int i = lane; i < N; i += 64) {
        const float* p = xyz + ((size_t)b * N + i) * 3;
        sxx[i] = p[0]; sxy[i] = p[1]; sxz[i] = p[2];
    }
    __syncthreads();
    float px[P], py[P], pz[P], dm[P];
    #pragma unroll
    for (int p = 0; p < P; p++) {
        int i = lane * P + p;
        px[p] = sxx[i]; py[p] = sxy[i]; pz[p] = sxz[i];
        dm[p] = 1e10f;
    }
    int last = 0;
    float lx = sxx[0], ly = sxy[0], lz = sxz[0];
    for (int j = 0; j < S; j++) {
        if (lane == 0) oidx[b * S + j] = last;
        float bv0 = -1.f, bv1 = -1.f; int bi0 = 0, bi1 = 0;
        #pragma unroll
        for (int p = 0; p < P; p++) {
            float dx = px[p] - lx, dy = py[p] - ly, dz = pz[p] - lz;
            float d2 = __fadd_rn(__fadd_rn(__fmul_rn(dx, dx), __fmul_rn(dy, dy)), __fmul_rn(dz, dz));
            float d = fminf(dm[p], d2); dm[p] = d;
            if (p & 1) { if (d > bv1) { bv1 = d; bi1 = lane * P + p; } }
            else       { if (d > bv0) { bv0 = d; bi0 = lane * P + p; } }
        }
        float bestv = bv0; int besti = bi0;
        cmb(bestv, besti, bv1, bi1);
        cmb(bestv, besti, dppf<0xB1>(bestv),  dppi<0xB1>(besti));
        cmb(bestv, besti, dppf<0x4E>(bestv),  dppi<0x4E>(besti));
        cmb(bestv, besti, dppf<0x141>(bestv), dppi<0x141>(besti));
        cmb(bestv, besti, dppf<0x140>(bestv), dppi<0x140>(besti));
        cmb(bestv, besti, dppf<0x142>(bestv), dppi<0x142>(besti));  // row_bcast15
        cmb(bestv, besti, dppf<0x143>(bestv), dppi<0x143>(besti));  // row_bcast31
        last = __builtin_amdgcn_readlane(besti, 63);
        lx = sxx[last]; ly = sxy[last]; lz = sxz[last];
    }
}

// ---------- ball query ----------
__global__ __launch_bounds__(256) void ball_query_kernel(
    const float* __restrict__ xyz, const int* __restrict__ cidx,
    int N, int S, int nsample, float r2,
    int* __restrict__ nidx, float* __restrict__ newxyz)
{
    __shared__ float sx[1280 * 3];
    int b = blockIdx.x, t = threadIdx.x;
    for (int i = t; i < N * 3; i += 256) sx[i] = xyz[(size_t)b * N * 3 + i];
    __syncthreads();
    int w = t >> 6, lane = t & 63;
    int s = blockIdx.y * 4 + w;
    if (s >= S) return;
    int c = cidx[b * S + s];
    float cx = sx[c * 3], cy = sx[c * 3 + 1], cz = sx[c * 3 + 2];
    if (lane == 0) {
        newxyz[((size_t)b * S + s) * 3 + 0] = cx;
        newxyz[((size_t)b * S + s) * 3 + 1] = cy;
        newxyz[((size_t)b * S + s) * 3 + 2] = cz;
    }
    int P = N >> 6;
    int base = lane * P;
    unsigned mask = 0;
    for (int p = 0; p < P; p++) {
        int i = base + p;
        float dx = sx[i * 3] - cx, dy = sx[i * 3 + 1] - cy, dz = sx[i * 3 + 2] - cz;
        float d2 = __fadd_rn(__fadd_rn(__fmul_rn(dx, dx), __fmul_rn(dy, dy)), __fmul_rn(dz, dz));
        if (d2 < r2) mask |= (1u << p);
    }
    int cnt = __popc(mask);
    int pre = cnt;
    for (int off = 1; off < 64; off <<= 1) {
        int v = __shfl_up(pre, off, 64);
        if (lane >= off) pre += v;
    }
    int excl = pre - cnt;
    int total = __shfl(pre, 63, 64);
    size_t outb = ((size_t)b * S + s) * (size_t)nsample;
    unsigned mm = mask; int pos = excl;
    while (mm) {
        int p = __ffs(mm) - 1; mm &= mm - 1;
        if (pos < nsample) nidx[outb + pos] = base + p;
        pos++;
    }
    unsigned long long bal = __ballot(cnt > 0);
    int firstlane = __ffsll(bal) - 1;
    int firstidx = base + __ffs(mask) - 1;
    firstidx = __shfl(firstidx, firstlane, 64);
    for (int p = total + lane; p < nsample; p += 64) nidx[outb + p] = firstidx;
}

// =====================================================================
// SA1 layer-a stats via second moments (exact, replaces stats GEMM pass)
// =====================================================================
__global__ __launch_bounds__(256) void sa1_moment_kernel(
    const float* __restrict__ xyz, const int* __restrict__ nidx,
    const float* __restrict__ nx, float* __restrict__ mom)
{
    float a[35];
    #pragma unroll
    for (int i = 0; i < 35; i++) a[i] = 0.f;
    int gid = blockIdx.x * 256 + threadIdx.x;
    for (int ch = 0; ch < 8; ch++) {
        int r = ch * 65536 + gid;
        int n = nidx[r];
        int bs = r >> 6, b = r >> 13;
        const float* p = xyz + ((size_t)b * 1280 + n) * 3;
        float cx = nx[bs * 3], cy = nx[bs * 3 + 1], cz = nx[bs * 3 + 2];
        float x[7];
        x[0] = p[0] - cx; x[1] = p[1] - cy; x[2] = p[2] - cz;
        x[3] = p[0]; x[4] = p[1]; x[5] = p[2];
        x[6] = (n < 1024) ? 1.f : 0.f;
        #pragma unroll
        for (int k = 0; k < 7; k++) a[k] += x[k];
        int idx = 7;
        #pragma unroll
        for (int k = 0; k < 7; k++)
            #pragma unroll
            for (int l = k; l < 7; l++) { a[idx] = fmaf(x[k], x[l], a[idx]); idx++; }
    }
    #pragma unroll
    for (int off = 32; off > 0; off >>= 1)
        #pragma unroll
        for (int i = 0; i < 35; i++) a[i] += __shfl_xor(a[i], off, 64);
    __shared__ float red[4][35];
    int wv = threadIdx.x >> 6, lane = threadIdx.x & 63;
    if (lane == 0) {
        #pragma unroll
        for (int i = 0; i < 35; i++) red[wv][i] = a[i];
    }
    __syncthreads();
    int t = threadIdx.x;
    if (t < 35) atomicAdd(&mom[t], red[0][t] + red[1][t] + red[2][t] + red[3][t]);
}

__global__ __launch_bounds__(64) void sa1_mom_fin_kernel(
    const float* __restrict__ mom, const float* __restrict__ w1a,
    float* __restrict__ osum, float* __restrict__ osq)
{
    int n = threadIdx.x;
    float wn[7];
    #pragma unroll
    for (int k = 0; k < 7; k++) wn[k] = w1a[(size_t)k * 64 + n];
    float s = 0.f;
    #pragma unroll
    for (int k = 0; k < 7; k++) s = fmaf(mom[k], wn[k], s);
    float q = 0.f;
    int idx = 7;
    #pragma unroll
    for (int k = 0; k < 7; k++)
        #pragma unroll
        for (int l = k; l < 7; l++) {
            float w2 = wn[k] * wn[l];
            q = fmaf(mom[idx], (k == l) ? w2 : 2.f * w2, q);
            idx++;
        }
    osum[n] = s; osq[n] = q;
}

// ---- SA1 AB (fused): gather, layer a, BN-a, layer b (K=64), write Y(b raw) + stats ----
__global__ __launch_bounds__(256, 4) void sa1_ab_kernel(
    const float* __restrict__ xyz, const int* __restrict__ nidx,
    const float* __restrict__ nx,
    const unsigned short* __restrict__ W1h, const unsigned short* __restrict__ W1l,
    const unsigned short* __restrict__ W2h, const unsigned short* __restrict__ W2l,
    const float* __restrict__ s1, const float* __restrict__ q1,
    const float* __restrict__ g1, const float* __restrict__ b1,
    float* __restrict__ ps, float* __restrict__ pq, float* __restrict__ Y)
{
    __shared__ unsigned short Xhi[64 * 40], Xlo[64 * 40];
    __shared__ unsigned short Hh[64 * 72], Hl[64 * 72];
    __shared__ float aA[64], aB[64];
    __shared__ float cs[64], cq[64];
    const float IR = 1.f / 524288.f;
    int bs = blockIdx.x, b = bs >> 7, t = threadIdx.x;
    if (t < 64) {
        float mu = s1[t] * IR;
        float rs = rsqrtf(q1[t] * IR - mu * mu + BN_EPS);
        float a = rs * g1[t];
        aA[t] = a; aB[t] = b1[t] - mu * a;
        int n = nidx[(size_t)bs * 64 + t];
        const float* p = xyz + ((size_t)b * 1280 + n) * 3;
        float cx = nx[bs * 3], cy = nx[bs * 3 + 1], cz = nx[bs * 3 + 2];
        float v[7] = { p[0] - cx, p[1] - cy, p[2] - cz, p[0], p[1], p[2], (n < 1024) ? 1.f : 0.f };
        #pragma unroll
        for (int k = 0; k < 7; k++) {
            unsigned short hi = f2b(v[k]);
            Xhi[t * 40 + k] = hi;
            Xlo[t * 40 + k] = f2b(v[k] - b2f(hi));
        }
        for (int k = 7; k < 40; k++) { Xhi[t * 40 + k] = 0; Xlo[t * 40 + k] = 0; }
    }
    __syncthreads();
    int wv = t >> 6, lane = t & 63;
    int quad = lane >> 4, l16 = lane & 15;
    int aoff = quad * 8;

    // layer a (12 MFMA)
    f32x4v acc[4] = {};
    {
        size_t woff = (size_t)(wv * 16 + l16) * 32 + aoff;
        s16x8 bh = *(const s16x8*)(W1h + woff);
        s16x8 bl = *(const s16x8*)(W1l + woff);
        #pragma unroll
        for (int mt = 0; mt < 4; mt++) {
            s16x8 ah = *(const s16x8*)&Xhi[(mt * 16 + l16) * 40 + aoff];
            s16x8 al = *(const s16x8*)&Xlo[(mt * 16 + l16) * 40 + aoff];
            acc[mt] = MFMA_B16(al, bh, acc[mt]);
            acc[mt] = MFMA_B16(ah, bl, acc[mt]);
            acc[mt] = MFMA_B16(ah, bh, acc[mt]);
        }
    }
    // BN-a + ReLU -> Hh/Hl (split bf16)
    {
        int n = wv * 16 + l16;
        float a = aA[n], bb = aB[n];
        #pragma unroll
        for (int mt = 0; mt < 4; mt++)
            #pragma unroll
            for (int r = 0; r < 4; r++) {
                int m = mt * 16 + quad * 4 + r;
                float h = fmaxf(acc[mt][r] * a + bb, 0.f);
                unsigned short hi = f2b(h);
                Hh[m * 72 + n] = hi;
                Hl[m * 72 + n] = f2b(h - b2f(hi));
            }
    }
    __syncthreads();

    // layer b (24 MFMA), write Y + stats
    f32x4v ac2[4] = {};
    #pragma unroll
    for (int kc = 0; kc < 64; kc += 32) {
        size_t woff = (size_t)(wv * 16 + l16) * 64 + kc + aoff;
        s16x8 bh = *(const s16x8*)(W2h + woff);
        s16x8 bl = *(const s16x8*)(W2l + woff);
        #pragma unroll
        for (int mt = 0; mt < 4; mt++) {
            s16x8 ah = *(const s16x8*)&Hh[(mt * 16 + l16) * 72 + kc + aoff];
            s16x8 al = *(const s16x8*)&Hl[(mt * 16 + l16) * 72 + kc + aoff];
            ac2[mt] = MFMA_B16(al, bh, ac2[mt]);
            ac2[mt] = MFMA_B16(ah, bl, ac2[mt]);
            ac2[mt] = MFMA_B16(ah, bh, ac2[mt]);
        }
    }
    int n = wv * 16 + l16;
    float s = 0.f, q = 0.f;
    #pragma unroll
    for (int mt = 0; mt < 4; mt++)
        #pragma unroll
        for (int r = 0; r < 4; r++) {
            int m = mt * 16 + quad * 4 + r;
            float v = ac2[mt][r];
            Y[((size_t)bs * 64 + m) * 64 + n] = v;
            s += v; q += v * v;
        }
    s += __shfl_xor(s, 16, 64); q += __shfl_xor(q, 16, 64);
    s += __shfl_xor(s, 32, 64); q += __shfl_xor(q, 32, 64);
    if (quad == 0) { cs[n] = s; cq[n] = q; }
    __syncthreads();
    if (t < 64) { ps[(size_t)bs * 64 + t] = cs[t]; pq[(size_t)bs * 64 + t] = cq[t]; }
}

// ---- SA1 C: 8 waves (512 thr), 2 groups/block, BN-b + layer c (128x128, K=64) ----
__global__ __launch_bounds__(512, 4) void sa1_c_kernel(
    const float* __restrict__ Y,
    const unsigned short* __restrict__ Wh, const unsigned short* __restrict__ Wl,
    const float* __restrict__ s2, const float* __restrict__ q2,
    const float* __restrict__ g2, const float* __restrict__ b2,
    float* __restrict__ ps, float* __restrict__ pq,
    float* __restrict__ pmax, float* __restrict__ pmin)
{
    __shared__ unsigned short Xhi[128 * 72], Xlo[128 * 72];
    __shared__ float aA[64], aB[64];
    __shared__ float cs2[2][128], cq2[2][128];
    __shared__ float cmx[2][128], cmn[2][128];
    const float IR = 1.f / 524288.f;
    int bs0 = blockIdx.x * 2;
    size_t rbase = (size_t)blockIdx.x * 128;
    int t = threadIdx.x;
    if (t < 64) {
        float mu = s2[t] * IR;
        float rs = rsqrtf(q2[t] * IR - mu * mu + BN_EPS);
        float a = rs * g2[t];
        aA[t] = a; aB[t] = b2[t] - mu * a;
    }
    __syncthreads();
    {
        int r = t >> 2, seg = t & 3;
        const float4* y4 = (const float4*)(Y + (rbase + r) * 64 + seg * 16);
        float4 v[4];
        #pragma unroll
        for (int i = 0; i < 4; i++) v[i] = y4[i];
        s16x8 ph[2], pl[2];
        #pragma unroll
        for (int i = 0; i < 4; i++) {
            #pragma unroll
            for (int j = 0; j < 4; j++) {
                int e = i * 4 + j;
                int c = seg * 16 + e;
                float x = fmaxf(((const float*)&v[i])[j] * aA[c] + aB[c], 0.f);
                unsigned short hi = f2b(x);
                ph[e >> 3][e & 7] = (short)hi;
                pl[e >> 3][e & 7] = (short)f2b(x - b2f(hi));
            }
        }
        #pragma unroll
        for (int k = 0; k < 2; k++) {
            *(s16x8*)&Xhi[r * 72 + seg * 16 + k * 8] = ph[k];
            *(s16x8*)&Xlo[r * 72 + seg * 16 + k * 8] = pl[k];
        }
    }
    __syncthreads();
    int wv = t >> 6, lane = t & 63;
    int wh = wv >> 2, wc = wv & 3;
    int quad = lane >> 4, l16 = lane & 15;
    int aoff = quad * 8;

    f32x4v a3[4][2] = {};
    #pragma unroll
    for (int kc = 0; kc < 64; kc += 32) {
        s16x8 ah[4], al[4];
        #pragma unroll
        for (int mi = 0; mi < 4; mi++) {
            int mt = wh * 4 + mi;
            ah[mi] = *(const s16x8*)&Xhi[(mt * 16 + l16) * 72 + kc + aoff];
            al[mi] = *(const s16x8*)&Xlo[(mt * 16 + l16) * 72 + kc + aoff];
        }
        #pragma unroll
        for (int nt = 0; nt < 2; nt++) {
            size_t woff = (size_t)(wc * 32 + nt * 16 + l16) * 64 + kc + aoff;
            s16x8 bh = *(const s16x8*)(Wh + woff);
            s16x8 bl = *(const s16x8*)(Wl + woff);
            #pragma unroll
            for (int mi = 0; mi < 4; mi++) {
                a3[mi][nt] = MFMA_B16(al[mi], bh, a3[mi][nt]);
                a3[mi][nt] = MFMA_B16(ah[mi], bl, a3[mi][nt]);
                a3[mi][nt] = MFMA_B16(ah[mi], bh, a3[mi][nt]);
            }
        }
    }
    #pragma unroll
    for (int nt = 0; nt < 2; nt++) {
        int n = wc * 32 + nt * 16 + l16;
        float s = 0.f, q = 0.f, mx = -3.4e38f, mn_ = 3.4e38f;
        #pragma unroll
        for (int mi = 0; mi < 4; mi++)
            #pragma unroll
            for (int r = 0; r < 4; r++) {
                float v = a3[mi][nt][r]; s += v; q += v * v;
                mx = fmaxf(mx, v); mn_ = fminf(mn_, v);
            }
        s += __shfl_xor(s, 16, 64); q += __shfl_xor(q, 16, 64);
        mx = fmaxf(mx, __shfl_xor(mx, 16, 64)); mn_ = fminf(mn_, __shfl_xor(mn_, 16, 64));
        s += __shfl_xor(s, 32, 64); q += __shfl_xor(q, 32, 64);
        mx = fmaxf(mx, __shfl_xor(mx, 32, 64)); mn_ = fminf(mn_, __shfl_xor(mn_, 32, 64));
        if (quad == 0) {
            cs2[wh][n] = s; cq2[wh][n] = q;
            cmx[wh][n] = mx; cmn[wh][n] = mn_;
        }
    }
    __syncthreads();
    if (t < 128) {
        ps[(size_t)blockIdx.x * 128 + t] = cs2[0][t] + cs2[1][t];
        pq[(size_t)blockIdx.x * 128 + t] = cq2[0][t] + cq2[1][t];
        pmax[(size_t)(bs0 + 0) * 128 + t] = cmx[0][t];
        pmin[(size_t)(bs0 + 0) * 128 + t] = cmn[0][t];
        pmax[(size_t)(bs0 + 1) * 128 + t] = cmx[1][t];
        pmin[(size_t)(bs0 + 1) * 128 + t] = cmn[1][t];
    }
}

// ---------- finalize SA1 pool -> BN+ReLU feature map FE1 (4 MB) ----------
__global__ __launch_bounds__(256) void bnpool_fin_kernel(
    const float* __restrict__ pmax, const float* __restrict__ pmin,
    const float* __restrict__ sum, const float* __restrict__ sq,
    const float* __restrict__ g, const float* __restrict__ bb,
    float rcnt, float* __restrict__ out, int total, int dmask)
{
    int i = blockIdx.x * 256 + threadIdx.x;
    if (i >= total) return;
    int d = i & dmask;
    float mu = sum[d] * rcnt;
    float rs = rsqrtf(sq[d] * rcnt - mu * mu + BN_EPS);
    float gv = g[d];
    float v = (gv >= 0.f) ? pmax[i] : pmin[i];
    out[i] = fmaxf((v - mu) * rs * gv + bb[d], 0.f);
}

// ---- SA2 A: 8 waves (512 thr), 64 rows/block, gather FE1, layer a (K=160) ----
__global__ __launch_bounds__(512, 4) void sa2_a_kernel(
    const float* __restrict__ xyz1, const int* __restrict__ nidx2,
    const float* __restrict__ nx2, const float* __restrict__ feat1,
    const unsigned short* __restrict__ Wh, const unsigned short* __restrict__ Wl,
    float* __restrict__ ps, float* __restrict__ pq, float* __restrict__ Y)
{
    __shared__ unsigned short Xhi[64 * 168], Xlo[64 * 168];
    __shared__ float cs[128], cq[128];
    __shared__ int sn[64];
    int row0 = blockIdx.x * 64;
    int bs = row0 >> 7, b = bs >> 5;
    int t = threadIdx.x;
    if (t < 64) sn[t] = nidx2[(size_t)bs * 128 + (row0 & 127) + t];
    __syncthreads();
    {
        int r = t >> 3, seg = t & 7;
        int n = sn[r];
        size_t base = ((size_t)(b * 128 + n)) * 128 + seg * 16;
        const float4* fr = (const float4*)(feat1 + base);
        float4 v[4];
        #pragma unroll
        for (int i = 0; i < 4; i++) v[i] = fr[i];
        s16x8 ph[2], pl[2];
        #pragma unroll
        for (int i = 0; i < 4; i++) {
            #pragma unroll
            for (int j = 0; j < 4; j++) {
                int e = i * 4 + j;
                float x = ((const float*)&v[i])[j];
                unsigned short hi = f2b(x);
                ph[e >> 3][e & 7] = (short)hi;
                pl[e >> 3][e & 7] = (short)f2b(x - b2f(hi));
            }
        }
        #pragma unroll
        for (int k = 0; k < 2; k++) {
            *(s16x8*)&Xhi[r * 168 + seg * 16 + k * 8] = ph[k];
            *(s16x8*)&Xlo[r * 168 + seg * 16 + k * 8] = pl[k];
        }
        if (seg == 0) {
            float c3x = nx2[bs * 3], c3y = nx2[bs * 3 + 1], c3z = nx2[bs * 3 + 2];
            const float* pz = xyz1 + ((size_t)b * 128 + n) * 3;
            float g3[3] = { pz[0] - c3x, pz[1] - c3y, pz[2] - c3z };
            s16x8 th = {0, 0, 0, 0, 0, 0, 0, 0}, tl = {0, 0, 0, 0, 0, 0, 0, 0};
            #pragma unroll
            for (int i = 0; i < 3; i++) {
                unsigned short hi = f2b(g3[i]);
                th[i] = (short)hi;
                tl[i] = (short)f2b(g3[i] - b2f(hi));
            }
            *(s16x8*)&Xhi[r * 168 + 128] = th;
            *(s16x8*)&Xlo[r * 168 + 128] = tl;
            s16x8 z = {0, 0, 0, 0, 0, 0, 0, 0};
            #pragma unroll
            for (int k = 0; k < 4; k++) {
                *(s16x8*)&Xhi[r * 168 + 136 + k * 8] = z;
                *(s16x8*)&Xlo[r * 168 + 136 + k * 8] = z;
            }
        }
    }
    __syncthreads();
    int wv = t >> 6, lane = t & 63;
    int quad = lane >> 4, l16 = lane & 15;
    int aoff = quad * 8;

    f32x4v acc[4] = {};
    #pragma unroll
    for (int kc = 0; kc < 160; kc += 32) {
        s16x8 ah[4], al[4];
        #pragma unroll
        for (int mt = 0; mt < 4; mt++) {
            ah[mt] = *(const s16x8*)&Xhi[(mt * 16 + l16) * 168 + kc + aoff];
            al[mt] = *(const s16x8*)&Xlo[(mt * 16 + l16) * 168 + kc + aoff];
        }
        size_t woff = (size_t)(wv * 16 + l16) * 160 + kc + aoff;
        s16x8 bh = *(const s16x8*)(Wh + woff);
        s16x8 bl = *(const s16x8*)(Wl + woff);
        #pragma unroll
        for (int mt = 0; mt < 4; mt++) {
            acc[mt] = MFMA_B16(al[mt], bh, acc[mt]);
            acc[mt] = MFMA_B16(ah[mt], bl, acc[mt]);
            acc[mt] = MFMA_B16(ah[mt], bh, acc[mt]);
        }
    }
    {
        int n = wv * 16 + l16;
        float s = 0.f, q = 0.f;
        #pragma unroll
        for (int mt = 0; mt < 4; mt++)
            #pragma unroll
            for (int r = 0; r < 4; r++) {
                int m = mt * 16 + quad * 4 + r;
                float v = acc[mt][r];
                Y[((size_t)row0 + m) * 128 + n] = v;
                s += v; q += v * v;
            }
        s += __shfl_xor(s, 16, 64); q += __shfl_xor(q, 16, 64);
        s += __shfl_xor(s, 32, 64); q += __shfl_xor(q, 32, 64);
        if (quad == 0) { cs[n] = s; cq[n] = q; }
    }
    __syncthreads();
    if (t < 128) { ps[(size_t)blockIdx.x * 128 + t] = cs[t]; pq[(size_t)blockIdx.x * 128 + t] = cq[t]; }
}

// ---- SA2 B: 8 waves (512 thr), 64 rows/block, BN-a + layer b (K=128), Y in place ----
__global__ __launch_bounds__(512, 4) void sa2_b_kernel(
    float* __restrict__ Y,
    const unsigned short* __restrict__ Wh, const unsigned short* __restrict__ Wl,
    const float* __restrict__ s1, const float* __restrict__ q1,
    const float* __restrict__ g1, const float* __restrict__ b1,
    float* __restrict__ ps, float* __restrict__ pq)
{
    __shared__ unsigned short Xhi[64 * 136], Xlo[64 * 136];
    __shared__ float aA[128], aB[128];
    __shared__ float cs[128], cq[128];
    const float IR = 1.f / 262144.f;
    int row0 = blockIdx.x * 64;
    int t = threadIdx.x;
    if (t < 128) {
        float mu = s1[t] * IR;
        float rs = rsqrtf(q1[t] * IR - mu * mu + BN_EPS);
        float a = rs * g1[t];
        aA[t] = a; aB[t] = b1[t] - mu * a;
    }
    __syncthreads();
    {
        int r = t >> 3, seg = t & 7;
        const float4* y4 = (const float4*)(Y + ((size_t)row0 + r) * 128 + seg * 16);
        float4 v[4];
        #pragma unroll
        for (int i = 0; i < 4; i++) v[i] = y4[i];
        s16x8 ph[2], pl[2];
        #pragma unroll
        for (int i = 0; i < 4; i++) {
            #pragma unroll
            for (int j = 0; j < 4; j++) {
                int e = i * 4 + j;
                int c = seg * 16 + e;
                float x = fmaxf(((const float*)&v[i])[j] * aA[c] + aB[c], 0.f);
                unsigned short hi = f2b(x);
                ph[e >> 3][e & 7] = (short)hi;
                pl[e >> 3][e & 7] = (short)f2b(x - b2f(hi));
            }
        }
        #pragma unroll
        for (int k = 0; k < 2; k++) {
            *(s16x8*)&Xhi[r * 136 + seg * 16 + k * 8] = ph[k];
            *(s16x8*)&Xlo[r * 136 + seg * 16 + k * 8] = pl[k];
        }
    }
    __syncthreads();
    int wv = t >> 6, lane = t & 63;
    int quad = lane >> 4, l16 = lane & 15;
    int aoff = quad * 8;

    f32x4v ac2[4] = {};
    #pragma unroll
    for (int kc = 0; kc < 128; kc += 32) {
        s16x8 ah[4], al[4];
        #pragma unroll
        for (int mt = 0; mt < 4; mt++) {
            ah[mt] = *(const s16x8*)&Xhi[(mt * 16 + l16) * 136 + kc + aoff];
            al[mt] = *(const s16x8*)&Xlo[(mt * 16 + l16) * 136 + kc + aoff];
        }
        size_t woff = (size_t)(wv * 16 + l16) * 128 + kc + aoff;
        s16x8 bh = *(const s16x8*)(Wh + woff);
        s16x8 bl = *(const s16x8*)(Wl + woff);
        #pragma unroll
        for (int mt = 0; mt < 4; mt++) {
            ac2[mt] = MFMA_B16(al[mt], bh, ac2[mt]);
            ac2[mt] = MFMA_B16(ah[mt], bl, ac2[mt]);
            ac2[mt] = MFMA_B16(ah[mt], bh, ac2[mt]);
        }
    }
    {
        int n = wv * 16 + l16;
        float s = 0.f, q = 0.f;
        #pragma unroll
        for (int mt = 0; mt < 4; mt++)
            #pragma unroll
            for (int r = 0; r < 4; r++) {
                int m = mt * 16 + quad * 4 + r;
                float v = ac2[mt][r];
                Y[((size_t)row0 + m) * 128 + n] = v;
                s += v; q += v * v;
            }
        s += __shfl_xor(s, 16, 64); q += __shfl_xor(q, 16, 64);
        s += __shfl_xor(s, 32, 64); q += __shfl_xor(q, 32, 64);
        if (quad == 0) { cs[n] = s; cq[n] = q; }
    }
    __syncthreads();
    if (t < 128) { ps[(size_t)blockIdx.x * 128 + t] = cs[t]; pq[(size_t)blockIdx.x * 128 + t] = cq[t]; }
}

// ---- SA2 C: 8 waves (512 thr), 64 rows/block, BN-b + layer c (64x256, K=128) ----
__global__ __launch_bounds__(512, 4) void sa2_c_kernel(
    const float* __restrict__ Y,
    const unsigned short* __restrict__ Wh, const unsigned short* __restrict__ Wl,
    const float* __restrict__ s2, const float* __restrict__ q2,
    const float* __restrict__ g2, const float* __restrict__ b2,
    float* __restrict__ ps, float* __restrict__ pq,
    unsigned* __restrict__ pmax, unsigned* __restrict__ pmin)
{
    __shared__ unsigned short Xhi[64 * 136], Xlo[64 * 136];
    __shared__ float aA[128], aB[128];
    __shared__ float cs[256], cq[256];
    __shared__ float cmx[256], cmn[256];
    const float IR = 1.f / 262144.f;
    int row0 = blockIdx.x * 64;
    int bs = row0 >> 7;
    int t = threadIdx.x;
    if (t < 128) {
        float mu = s2[t] * IR;
        float rs = rsqrtf(q2[t] * IR - mu * mu + BN_EPS);
        float a = rs * g2[t];
        aA[t] = a; aB[t] = b2[t] - mu * a;
    }
    __syncthreads();
    {
        int r = t >> 3, seg = t & 7;
        const float4* y4 = (const float4*)(Y + ((size_t)row0 + r) * 128 + seg * 16);
        float4 v[4];
        #pragma unroll
        for (int i = 0; i < 4; i++) v[i] = y4[i];
        s16x8 ph[2], pl[2];
        #pragma unroll
        for (int i = 0; i < 4; i++) {
            #pragma unroll
            for (int j = 0; j < 4; j++) {
                int e = i * 4 + j;
                int c = seg * 16 + e;
                float x = fmaxf(((const float*)&v[i])[j] * aA[c] + aB[c], 0.f);
                unsigned short hi = f2b(x);
                ph[e >> 3][e & 7] = (short)hi;
                pl[e >> 3][e & 7] = (short)f2b(x - b2f(hi));
            }
        }
        #pragma unroll
        for (int k = 0; k < 2; k++) {
            *(s16x8*)&Xhi[r * 136 + seg * 16 + k * 8] = ph[k];
            *(s16x8*)&Xlo[r * 136 + seg * 16 + k * 8] = pl[k];
        }
    }
    __syncthreads();
    int wv = t >> 6, lane = t & 63;
    int quad = lane >> 4, l16 = lane & 15;
    int aoff = quad * 8;

    f32x4v a3[4][2] = {};
    #pragma unroll
    for (int kc = 0; kc < 128; kc += 32) {
        s16x8 ah[4], al[4];
        #pragma unroll
        for (int mt = 0; mt < 4; mt++) {
            ah[mt] = *(const s16x8*)&Xhi[(mt * 16 + l16) * 136 + kc + aoff];
            al[mt] = *(const s16x8*)&Xlo[(mt * 16 + l16) * 136 + kc + aoff];
        }
        #pragma unroll
        for (int ct = 0; ct < 2; ct++) {
            size_t woff = (size_t)(wv * 32 + ct * 16 + l16) * 128 + kc + aoff;
            s16x8 bh = *(const s16x8*)(Wh + woff);
            s16x8 bl = *(const s16x8*)(Wl + woff);
            #pragma unroll
            for (int mt = 0; mt < 4; mt++) {
                a3[mt][ct] = MFMA_B16(al[mt], bh, a3[mt][ct]);
                a3[mt][ct] = MFMA_B16(ah[mt], bl, a3[mt][ct]);
                a3[mt][ct] = MFMA_B16(ah[mt], bh, a3[mt][ct]);
            }
        }
    }
    #pragma unroll
    for (int ct = 0; ct < 2; ct++) {
        int n = wv * 32 + ct * 16 + l16;
        float s = 0.f, q = 0.f, mx = -3.4e38f, mn = 3.4e38f;
        #pragma unroll
        for (int mt = 0; mt < 4; mt++)
            #pragma unroll
            for (int r = 0; r < 4; r++) {
                float v = a3[mt][ct][r]; s += v; q += v * v;
                mx = fmaxf(mx, v); mn = fminf(mn, v);
            }
        s += __shfl_xor(s, 16, 64); q += __shfl_xor(q, 16, 64);
        mx = fmaxf(mx, __shfl_xor(mx, 16, 64)); mn = fminf(mn, __shfl_xor(mn, 16, 64));
        s += __shfl_xor(s, 32, 64); q += __shfl_xor(q, 32, 64);
        mx = fmaxf(mx, __shfl_xor(mx, 32, 64)); mn = fminf(mn, __shfl_xor(mn, 32, 64));
        if (quad == 0) { cs[n] = s; cq[n] = q; cmx[n] = mx; cmn[n] = mn; }
    }
    __syncthreads();
    if (t < 256) {
        ps[(size_t)blockIdx.x * 256 + t] = cs[t]; pq[(size_t)blockIdx.x * 256 + t] = cq[t];
        atomicMax(&pmax[(size_t)bs * 256 + t], fenc(cmx[t]));
        atomicMin(&pmin[(size_t)bs * 256 + t], fenc(cmn[t]));
    }
}

// ---------- build SA3 input (2048 x 259) ----------
__global__ __launch_bounds__(256) void grouped3_prep_kernel(
    const float* __restrict__ nx2, const unsigned* __restrict__ pmax,
    const unsigned* __restrict__ pmin, const float* __restrict__ sum,
    const float* __restrict__ sq, const float* __restrict__ g,
    const float* __restrict__ bb, float rcnt, float* __restrict__ out)
{
    int row = blockIdx.x;
    int t = threadIdx.x;
    for (int c = t; c < 259; c += 256) {
        float v;
        if (c < 3) v = nx2[row * 3 + c];
        else {
            int d = c - 3;
            float mu = sum[d] * rcnt;
            float rs = rsqrtf(sq[d] * rcnt - mu * mu + BN_EPS);
            float gv = g[d];
            float x = fdec((gv >= 0.f) ? pmax[(size_t)row * 256 + d] : pmin[(size_t)row * 256 + d]);
            v = fmaxf((x - mu) * rs * gv + bb[d], 0.f);
        }
        out[(size_t)row * 259 + c] = v;
    }
}

// ---------- generic GEMM (SA3) ----------
__global__ __launch_bounds__(256) void gemm_bn_kernel(
    const float* __restrict__ X, const float* __restrict__ W,
    const float* __restrict__ bias, float* __restrict__ Y,
    const float* __restrict__ isum, const float* __restrict__ isq,
    const float* __restrict__ ig, const float* __restrict__ ib, float ircnt,
    float* __restrict__ osum, float* __restrict__ osq,
    int M, int C, int D)
{
    __shared__ float Xs[64 * 33];
    __shared__ float Ws[32 * 64];
    __shared__ float cs[64], cq[64];
    int m0 = blockIdx.x * 64;
    int d0 = blockIdx.y * 64;
    int t = threadIdx.x;
    int tr = t >> 4, tc = t & 15, r0 = tr * 4, c0 = tc * 4;
    float acc[4][4] = {};
    int nchunk = (C + 31) / 32;
    for (int ch = 0; ch < nchunk; ch++) {
        int kbase = ch * 32;
        for (int f = t; f < 64 * 32; f += 256) {
            int r = f >> 5, c = f & 31; int gc = kbase + c;
            float v = 0.f;
            if (gc < C) {
                v = X[(size_t)(m0 + r) * C + gc];
                if (isum) {
                    float mu = isum[gc] * ircnt;
                    float rs = rsqrtf(isq[gc] * ircnt - mu * mu + BN_EPS);
                    v = fmaxf((v - mu) * rs * ig[gc] + ib[gc], 0.f);
                }
            }
            Xs[r * 33 + c] = v;
        }
        for (int f = t; f < 32 * 64; f += 256) {
            int c = f >> 6, j = f & 63; int gc = kbase + c;
            Ws[f] = (gc < C) ? W[(size_t)gc * D + d0 + j] : 0.f;
        }
        __syncthreads();
        #pragma unroll 8
        for (int kk = 0; kk < 32; kk++) {
            float xv[4], wv[4];
            #pragma unroll
            for (int i = 0; i < 4; i++) xv[i] = Xs[(r0 + i) * 33 + kk];
            #pragma unroll
            for (int j = 0; j < 4; j++) wv[j] = Ws[kk * 64 + c0 + j];
            #pragma unroll
            for (int i = 0; i < 4; i++)
                #pragma unroll
                for (int j = 0; j < 4; j++)
                    acc[i][j] = fmaf(xv[i], wv[j], acc[i][j]);
        }
        __syncthreads();
    }
    if (bias) {
        #pragma unroll
        for (int j = 0; j < 4; j++) {
            float bv = bias[d0 + c0 + j];
            #pragma unroll
            for (int i = 0; i < 4; i++) acc[i][j] += bv;
        }
    }
    #pragma unroll
    for (int i = 0; i < 4; i++) {
        float4 v = make_float4(acc[i][0], acc[i][1], acc[i][2], acc[i][3]);
        *(float4*)(Y + (size_t)(m0 + r0 + i) * D + d0 + c0) = v;
    }
    if (t < 64) { cs[t] = 0.f; cq[t] = 0.f; }
    __syncthreads();
    #pragma unroll
    for (int j = 0; j < 4; j++) {
        int col = c0 + j;
        float s = 0.f, q = 0.f;
        #pragma unroll
        for (int i = 0; i < 4; i++) { float v = acc[i][j]; s += v; q += v * v; }
        atomicAdd(&cs[col], s); atomicAdd(&cq[col], q);
    }
    __syncthreads();
    if (t < 64) { atomicAdd(&osum[d0 + t], cs[t]); atomicAdd(&osq[d0 + t], cq[t]); }
}

// ---------- FC split-K GEMM ----------
__global__ __launch_bounds__(256) void fc_gemm_kernel(
    const float* __restrict__ X, const float* __restrict__ W,
    const float* __restrict__ isum, const float* __restrict__ isq,
    const float* __restrict__ ig, const float* __restrict__ ib, float ircnt,
    float* __restrict__ PP, int C, int D)
{
    __shared__ float Xs[64 * 132];
    int d0 = blockIdx.x * 64;
    int KS = gridDim.y;
    int L = C / KS;
    int kbase = blockIdx.y * L;
    int t = threadIdx.x;
    for (int f = t; f < 64 * L; f += 256) {
        int r = f / L, k = f - r * L;
        int gc = kbase + k;
        float v = X[(size_t)r * C + gc];
        if (isum) {
            float mu = isum[gc] * ircnt;
            float rs = rsqrtf(isq[gc] * ircnt - mu * mu + BN_EPS);
            v = fmaxf((v - mu) * rs * ig[gc] + ib[gc], 0.f);
        }
        Xs[r * 132 + k] = v;
    }
    __syncthreads();
    int tr = t >> 4, tc = t & 15, r0 = tr * 4, c0 = tc * 4;
    float acc[4][4] = {};
    for (int k = 0; k < L; k++) {
        float xv[4];
        #pragma unroll
        for (int i = 0; i < 4; i++) xv[i] = Xs[(r0 + i) * 132 + k];
        float4 wv = *(const float4*)(W + (size_t)(kbase + k) * D + d0 + c0);
        #pragma unroll
        for (int i = 0; i < 4; i++) {
            acc[i][0] = fmaf(xv[i], wv.x, acc[i][0]);
            acc[i][1] = fmaf(xv[i], wv.y, acc[i][1]);
            acc[i][2] = fmaf(xv[i], wv.z, acc[i][2]);
            acc[i][3] = fmaf(xv[i], wv.w, acc[i][3]);
        }
    }
    float* pp = PP + (size_t)blockIdx.y * 64 * D;
    #pragma unroll
    for (int i = 0; i < 4; i++) {
        float4 v = make_float4(acc[i][0], acc[i][1], acc[i][2], acc[i][3]);
        *(float4*)(pp + (size_t)(r0 + i) * D + d0 + c0) = v;
    }
}

// ---------- FC finalize + fused column stats (osum/osq pre-zeroed) ----------
__global__ __launch_bounds__(256) void fc_fin_kernel(
    const float* __restrict__ PP, const float* __restrict__ bias,
    int D, int KS, float* __restrict__ Y,
    float* __restrict__ osum, float* __restrict__ osq)
{
    int i = blockIdx.x * 256 + threadIdx.x;
    if (i >= 64 * D) return;
    int n = i % D;
    float s = 0.f;
    for (int k = 0; k < KS; k++) s += PP[(size_t)k * 64 * D + i];
    float y = s + bias[n];
    Y[i] = y;
    atomicAdd(&osum[n], y);
    atomicAdd(&osq[n], y * y);
}

// ---------- SA3 pool ----------
__global__ __launch_bounds__(256) void pool3_kernel(
    const float* __restrict__ h, const float* __restrict__ sum,
    const float* __restrict__ sq, const float* __restrict__ g,
    const float* __restrict__ bb, float* __restrict__ out)
{
    int i = blockIdx.x * 256 + threadIdx.x;
    if (i >= 32768) return;
    int d = i & 511, b = i >> 9;
    const float rcnt = 1.f / 2048.f;
    float mu = sum[d] * rcnt;
    float rs = rsqrtf(sq[d] * rcnt - mu * mu + BN_EPS);
    float gv = g[d], bv = bb[d];
    float m = -3.4e38f;
    for (int k = 0; k < 32; k++) {
        float v = h[((size_t)b * 32 + k) * 512 + d];
        m = fmaxf(m, fmaxf((v - mu) * rs * gv + bv, 0.f));
    }
    out[i] = m;
}

// ---------- head ----------
__global__ __launch_bounds__(256) void head_kernel(
    const float* __restrict__ y2, const float* __restrict__ sum,
    const float* __restrict__ sq, const float* __restrict__ g,
    const float* __restrict__ bb, const float* __restrict__ hw,
    const float* __restrict__ hb, float* __restrict__ out)
{
    __shared__ float red[256];
    int b = blockIdx.x, t = threadIdx.x;
    const float rcnt = 1.f / 64.f;
    float part = 0.f;
    for (int d = t; d < 1024; d += 256) {
        float mu = sum[d] * rcnt;
        float rs = rsqrtf(sq[d] * rcnt - mu * mu + BN_EPS);
        float v = fmaxf((y2[(size_t)b * 1024 + d] - mu) * rs * g[d] + bb[d], 0.f);
        part = fmaf(v, hw[d], part);
    }
    red[t] = part; __syncthreads();
    if (t < 128) red[t] += red[t + 128];
    __syncthreads();
    if (t < 64) {
        float v = red[t] + red[t + 64];
        for (int off = 32; off > 0; off >>= 1) v += __shfl_down(v, off, 64);
        if (t == 0) out[b] = v + hb[0];
    }
}

extern "C" void kernel_launch(void* const* d_in, const int* in_sizes, int n_in,
                              void* d_out, int out_size, void* d_ws, size_t ws_size,
                              hipStream_t stream)
{
    (void)in_sizes; (void)n_in; (void)out_size; (void)ws_size;
    const float* pc  = (const float*)d_in[0];
    const float* gpc = (const float*)d_in[1];
    const float* w1a = (const float*)d_in[2];  const float* g1a = (const float*)d_in[3];  const float* b1a = (const float*)d_in[4];
    const float* w1b = (const float*)d_in[5];  const float* g1b = (const float*)d_in[6];  const float* b1b = (const float*)d_in[7];
    const float* w1c = (const float*)d_in[8];  const float* g1c = (const float*)d_in[9];  const float* b1c = (const float*)d_in[10];
    const float* w2a = (const float*)d_in[11]; const float* g2a = (const float*)d_in[12]; const float* b2a = (const float*)d_in[13];
    const float* w2b = (const float*)d_in[14]; const float* g2b = (const float*)d_in[15]; const float* b2b = (const float*)d_in[16];
    const float* w2c = (const float*)d_in[17]; const float* g2c = (const float*)d_in[18]; const float* b2c = (const float*)d_in[19];
    const float* w3a = (const float*)d_in[20]; const float* g3a = (const float*)d_in[21]; const float* b3a = (const float*)d_in[22];
    const float* w3b = (const float*)d_in[23]; const float* g3b = (const float*)d_in[24]; const float* b3b = (const float*)d_in[25];
    const float* w3c = (const float*)d_in[26]; const float* g3c = (const float*)d_in[27]; const float* b3c = (const float*)d_in[28];
    const float* fw1 = (const float*)d_in[29]; const float* fb1 = (const float*)d_in[30];
    const float* fg1 = (const float*)d_in[31]; const float* fbb1 = (const float*)d_in[32];
    const float* fw2 = (const float*)d_in[33]; const float* fb2 = (const float*)d_in[34];
    const float* fg2 = (const float*)d_in[35]; const float* fbb2 = (const float*)d_in[36];
    const float* hw  = (const float*)d_in[37]; const float* hb  = (const float*)d_in[38];
    float* out = (float*)d_out;

    char* ws = (char*)d_ws;
    size_t o = 0;
    auto take = [&](size_t nf) { size_t r = o; o += nf * 4; return r; };
    size_t XYZ  = take(245760);
    size_t CID1 = take(8192);
    size_t NID1 = take(524288);
    size_t NX1  = take(24576);
    size_t CID2 = take(2048);
    size_t NID2 = take(262144);
    size_t NX2  = take(6144);
    size_t FE1  = take(1048576);      // (64,128,128) BN'd SA1 features
    size_t GR3  = take(530432);
    size_t H3A  = take(524288);
    size_t H3B  = take(524288);
    size_t H3C  = take(1048576);
    size_t X3   = take(32768);
    size_t Y1   = take(65536);
    size_t Y2   = take(65536);
    size_t P1X  = take(1048576);
    size_t P1N  = take(1048576);
    size_t WT1H = take(10240);
    size_t WT1L = take(10240);
    size_t WT2H = take(8192);
    size_t WT2L = take(8192);
    size_t WT3H = take(16384);
    size_t WT3L = take(16384);
    size_t WA1H = take(1024);
    size_t WA1L = take(1024);
    size_t WB1H = take(2048);
    size_t WB1L = take(2048);
    size_t WC1H = take(4096);
    size_t WC1L = take(4096);
    size_t Z0   = o;
    size_t STT  = take(11 * 2048);
    size_t MOM  = take(64);
    size_t P2X  = take(524288);
    size_t Z1   = o;
    size_t P2N  = take(524288);
    size_t Z2   = o;
    size_t PSB  = take(2097152);
    size_t PQB  = take(2097152);
    size_t YB   = take(33554432);

    #define Fp(x) ((float*)(ws + (x)))
    #define Ip(x) ((int*)(ws + (x)))
    #define Up(x) ((unsigned*)(ws + (x)))
    #define Hp(x) ((unsigned short*)(ws + (x)))
    auto st = [&](int slot) { return Fp(STT + (size_t)slot * 2048 * 4); };

    hipMemsetAsync(ws + Z0, 0, Z1 - Z0, stream);
    hipMemsetAsync(ws + Z1, 0xFF, Z2 - Z1, stream);

    build_xyz_kernel<<<320, 256, 0, stream>>>(pc, gpc, Fp(XYZ));
    prep_w_kernel<<<328, 256, 0, stream>>>(w2a, w2b, w2c, w1a, w1b, w1c,
        Hp(WT1H), Hp(WT1L), Hp(WT2H), Hp(WT2L), Hp(WT3H), Hp(WT3L),
        Hp(WA1H), Hp(WA1L), Hp(WB1H), Hp(WB1L), Hp(WC1H), Hp(WC1L));

    // ---- SA1 ----
    fps_mw_kernel<5><<<64, 256, 0, stream>>>(Fp(XYZ), 1280, 128, Ip(CID1));
    ball_query_kernel<<<dim3(64, 32), 256, 0, stream>>>(Fp(XYZ), Ip(CID1), 1280, 128, 64,
                                                        (float)(0.02 * 0.02), Ip(NID1), Fp(NX1));
    sa1_moment_kernel<<<256, 256, 0, stream>>>(Fp(XYZ), Ip(NID1), Fp(NX1), Fp(MOM));
    sa1_mom_fin_kernel<<<1, 64, 0, stream>>>(Fp(MOM), w1a, st(0), st(0) + 1024);
    sa1_ab_kernel<<<8192, 256, 0, stream>>>(Fp(XYZ), Ip(NID1), Fp(NX1),
        Hp(WA1H), Hp(WA1L), Hp(WB1H), Hp(WB1L),
        st(0), st(0) + 1024, g1a, b1a, Fp(PSB), Fp(PQB), Fp(YB));
    reduce_stats_kernel<<<dim3(64, 8), 256, 0, stream>>>(Fp(PSB), Fp(PQB), 8192, 64,
        st(1), st(1) + 1024);
    sa1_c_kernel<<<4096, 512, 0, stream>>>(Fp(YB), Hp(WC1H), Hp(WC1L),
        st(1), st(1) + 1024, g1b, b1b, Fp(PSB), Fp(PQB), Fp(P1X), Fp(P1N));
    reduce_stats_kernel<<<dim3(128, 8), 256, 0, stream>>>(Fp(PSB), Fp(PQB), 4096, 128,
        st(2), st(2) + 1024);
    bnpool_fin_kernel<<<4096, 256, 0, stream>>>(Fp(P1X), Fp(P1N), st(2), st(2) + 1024,
                                                g1c, b1c, 1.f / 524288.f, Fp(FE1), 1048576, 127);

    // ---- SA2 ----
    fps_wave_kernel<2><<<64, 64, 0, stream>>>(Fp(NX1), 128, 32, Ip(CID2));
    ball_query_kernel<<<dim3(64, 8), 256, 0, stream>>>(Fp(NX1), Ip(CID2), 128, 32, 128,
                                                       (float)(0.04 * 0.04), Ip(NID2), Fp(NX2));
    sa2_a_kernel<<<4096, 512, 0, stream>>>(Fp(NX1), Ip(NID2), Fp(NX2), Fp(FE1),
        Hp(WT1H), Hp(WT1L), Fp(PSB), Fp(PQB), Fp(YB));
    reduce_stats_kernel<<<dim3(128, 8), 256, 0, stream>>>(Fp(PSB), Fp(PQB), 4096, 128,
        st(3), st(3) + 1024);
    sa2_b_kernel<<<4096, 512, 0, stream>>>(Fp(YB), Hp(WT2H), Hp(WT2L),
        st(3), st(3) + 1024, g2a, b2a, Fp(PSB), Fp(PQB));
    reduce_stats_kernel<<<dim3(128, 8), 256, 0, stream>>>(Fp(PSB), Fp(PQB), 4096, 128,
        st(4), st(4) + 1024);
    sa2_c_kernel<<<4096, 512, 0, stream>>>(Fp(YB), Hp(WT3H), Hp(WT3L),
        st(4), st(4) + 1024, g2b, b2b, Fp(PSB), Fp(PQB), Up(P2X), Up(P2N));
    reduce_stats_kernel<<<dim3(256, 8), 256, 0, stream>>>(Fp(PSB), Fp(PQB), 4096, 256,
        st(5), st(5) + 1024);

    // ---- SA3 ----
    grouped3_prep_kernel<<<2048, 256, 0, stream>>>(Fp(NX2), Up(P2X), Up(P2N),
        st(5), st(5) + 1024, g2c, b2c, 1.f / 262144.f, Fp(GR3));
    gemm_bn_kernel<<<dim3(32, 4), 256, 0, stream>>>(Fp(GR3), w3a, nullptr, Fp(H3A),
        nullptr, nullptr, nullptr, nullptr, 0.f, st(6), st(6) + 1024, 2048, 259, 256);
    gemm_bn_kernel<<<dim3(32, 4), 256, 0, stream>>>(Fp(H3A), w3b, nullptr, Fp(H3B),
        st(6), st(6) + 1024, g3a, b3a, 1.f / 2048.f, st(7), st(7) + 1024, 2048, 256, 256);
    gemm_bn_kernel<<<dim3(32, 8), 256, 0, stream>>>(Fp(H3B), w3c, nullptr, Fp(H3C),
        st(7), st(7) + 1024, g3b, b3b, 1.f / 2048.f, st(8), st(8) + 1024, 2048, 256, 512);
    pool3_kernel<<<128, 256, 0, stream>>>(Fp(H3C), st(8), st(8) + 1024, g3c, b3c, Fp(X3));

    // ---- FC head (split-K, KS=16; col-stats fused into fc_fin) ----
    fc_gemm_kernel<<<dim3(16, 16), 256, 0, stream>>>(Fp(X3), fw1,
        nullptr, nullptr, nullptr, nullptr, 0.f, Fp(PSB), 512, 1024);
    fc_fin_kernel<<<256, 256, 0, stream>>>(Fp(PSB), fb1, 1024, 16, Fp(Y1),
        st(9), st(9) + 1024);
    fc_gemm_kernel<<<dim3(16, 16), 256, 0, stream>>>(Fp(Y1), fw2,
        st(9), st(9) + 1024, fg1, fbb1, 1.f / 64.f, Fp(PSB), 1024, 1024);
    fc_fin_kernel<<<256, 256, 0, stream>>>(Fp(PSB), fb2, 1024, 16, Fp(Y2),
        st(10), st(10) + 1024);
    head_kernel<<<64, 256, 0, stream>>>(Fp(Y2), st(10), st(10) + 1024, fg2, fbb2, hw, hb, out);

    #undef Fp
    #undef Ip
    #undef Up
    #undef Hp
}

// Round 14
// 822.871 us; speedup vs baseline: 1.0122x; 1.0122x over previous
//
#include <hip/hip_runtime.h>

#define BN_EPS 1e-5f
#define MFMA_B16(a, b, c) __builtin_amdgcn_mfma_f32_16x16x32_bf16((a), (b), (c), 0, 0, 0)

typedef short s16x8 __attribute__((ext_vector_type(8)));
typedef float f32x4v __attribute__((ext_vector_type(4)));

__device__ __forceinline__ unsigned fenc(float f) {
    unsigned u = __float_as_uint(f);
    return (u & 0x80000000u) ? ~u : (u | 0x80000000u);
}
__device__ __forceinline__ float fdec(unsigned e) {
    unsigned u = (e & 0x80000000u) ? (e ^ 0x80000000u) : ~e;
    return __uint_as_float(u);
}
__device__ __forceinline__ unsigned short f2b(float f) {
    unsigned u = __float_as_uint(f);
    unsigned r = u + 0x7FFFu + ((u >> 16) & 1u);
    return (unsigned short)(r >> 16);
}
__device__ __forceinline__ float b2f(unsigned short h) {
    return __uint_as_float(((unsigned)h) << 16);
}

// argmax combine with first-max (lowest index) tie-break
__device__ __forceinline__ void cmb(float& v, int& i, float ov, int oi) {
    bool t = (ov > v) || ((ov == v) && (oi < i));
    v = t ? ov : v;
    i = t ? oi : i;
}
// same, carrying winner coords
__device__ __forceinline__ void cmb5(float& v, int& i, float& x, float& y, float& z,
                                     float ov, int oi, float ox, float oy, float oz) {
    bool t = (ov > v) || ((ov == v) && (oi < i));
    v = t ? ov : v; i = t ? oi : i;
    x = t ? ox : x; y = t ? oy : y; z = t ? oz : z;
}
template<int CTRL>
__device__ __forceinline__ float dppf(float x) {
    return __uint_as_float((unsigned)__builtin_amdgcn_update_dpp(
        0, (int)__float_as_uint(x), CTRL, 0xF, 0xF, true));
}
template<int CTRL>
__device__ __forceinline__ int dppi(int x) {
    return __builtin_amdgcn_update_dpp(0, x, CTRL, 0xF, 0xF, true);
}

// ---------- build concatenated xyz (B,1280,3) ----------
__global__ __launch_bounds__(256) void build_xyz_kernel(
    const float* __restrict__ pc, const float* __restrict__ gpc, float* __restrict__ xyz)
{
    int p = blockIdx.x * 256 + threadIdx.x;
    if (p >= 64 * 1280) return;
    int b = p / 1280, i = p % 1280;
    const float* src = (i < 1024) ? (pc + ((size_t)b * 1024 + i) * 3)
                                  : (gpc + ((size_t)b * 256 + (i - 1024)) * 3);
    xyz[(size_t)p * 3 + 0] = src[0];
    xyz[(size_t)p * 3 + 1] = src[1];
    xyz[(size_t)p * 3 + 2] = src[2];
}

// ---------- prep: transpose SA1+SA2 weights to split-bf16 W^T[n][k] (hi+lo) ----------
__global__ __launch_bounds__(256) void prep_w_kernel(
    const float* __restrict__ w2a, const float* __restrict__ w2b, const float* __restrict__ w2c,
    const float* __restrict__ w1a, const float* __restrict__ w1b, const float* __restrict__ w1c,
    unsigned short* __restrict__ W1Th, unsigned short* __restrict__ W1Tl,
    unsigned short* __restrict__ W2Th, unsigned short* __restrict__ W2Tl,
    unsigned short* __restrict__ W3Th, unsigned short* __restrict__ W3Tl,
    unsigned short* __restrict__ A1Th, unsigned short* __restrict__ A1Tl,
    unsigned short* __restrict__ B1Th, unsigned short* __restrict__ B1Tl,
    unsigned short* __restrict__ C1Th, unsigned short* __restrict__ C1Tl)
{
    int i = blockIdx.x * 256 + threadIdx.x;
    float v = 0.f;
    unsigned short* dh; unsigned short* dl; int j;
    if (i < 20480) {                       // SA2 W1T 128 x 160
        int n = i / 160, k = i % 160;
        if (k < 128)       v = w2a[(size_t)(3 + k) * 128 + n];
        else if (k < 131)  v = w2a[(size_t)(k - 128) * 128 + n];
        dh = W1Th; dl = W1Tl; j = i;
    } else if (i < 36864) {                // SA2 W2T 128 x 128
        j = i - 20480;
        int n = j / 128, k = j % 128;
        v = w2b[(size_t)k * 128 + n];
        dh = W2Th; dl = W2Tl;
    } else if (i < 69632) {                // SA2 W3T 256 x 128
        j = i - 36864;
        int n = j / 128, k = j % 128;
        v = w2c[(size_t)k * 256 + n];
        dh = W3Th; dl = W3Tl;
    } else if (i < 71680) {                // SA1 A1T 64 x 32
        j = i - 69632;
        int n = j / 32, k = j % 32;
        if (k < 7) v = w1a[(size_t)k * 64 + n];
        dh = A1Th; dl = A1Tl;
    } else if (i < 75776) {                // SA1 B1T 64 x 64
        j = i - 71680;
        int n = j / 64, k = j % 64;
        v = w1b[(size_t)k * 64 + n];
        dh = B1Th; dl = B1Tl;
    } else if (i < 83968) {                // SA1 C1T 128 x 64
        j = i - 75776;
        int n = j / 64, k = j % 64;
        v = w1c[(size_t)k * 128 + n];
        dh = C1Th; dl = C1Tl;
    } else return;
    unsigned short hi = f2b(v);
    unsigned short lo = f2b(v - b2f(hi));
    dh[j] = hi; dl[j] = lo;
}

// ---------- reduce per-block stat partials (row-split, atomic accumulate) ----------
__global__ __launch_bounds__(256) void reduce_stats_kernel(
    const float* __restrict__ PS, const float* __restrict__ PQ,
    int nblk, int C, float* __restrict__ osum, float* __restrict__ osq)
{
    __shared__ float rs_[256], rq_[256];
    int c = blockIdx.x, t = threadIdx.x;
    int L = nblk / gridDim.y;
    int r0 = blockIdx.y * L;
    float s = 0.f, q = 0.f;
    for (int i = r0 + t; i < r0 + L; i += 256) {
        s += PS[(size_t)i * C + c];
        q += PQ[(size_t)i * C + c];
    }
    rs_[t] = s; rq_[t] = q;
    __syncthreads();
    for (int off = 128; off >= 1; off >>= 1) {
        if (t < off) { rs_[t] += rs_[t + off]; rq_[t] += rq_[t + off]; }
        __syncthreads();
    }
    if (t == 0) { atomicAdd(&osum[c], rs_[0]); atomicAdd(&osq[c], rq_[0]); }
}

// ---------- FPS multi-wave: 4 waves/batch, P points/thread, SoA LDS ----------
template<int P>
__global__ __launch_bounds__(256, 1) void fps_mw_kernel(
    const float* __restrict__ xyz, int N, int S, int* __restrict__ oidx)
{
    __shared__ float sxx[1280], sxy[1280], sxz[1280];
    __shared__ float rv[2][4];
    __shared__ int   ri[2][4];
    int b = blockIdx.x, t = threadIdx.x;
    int wv = t >> 6, lane = t & 63;
    for (int i = t; i < N; i += 256) {
        const float* p = xyz + ((size_t)b * N + i) * 3;
        sxx[i] = p[0]; sxy[i] = p[1]; sxz[i] = p[2];
    }
    __syncthreads();
    float px[P], py[P], pz[P], dm[P];
    #pragma unroll
    for (int p = 0; p < P; p++) {
        int i = t * P + p;
        px[p] = sxx[i]; py[p] = sxy[i]; pz[p] = sxz[i];
        dm[p] = 1e10f;
    }
    int last = 0;
    float lx = sxx[0], ly = sxy[0], lz = sxz[0];
    for (int j = 0; j < S; j++) {
        if (t == 0) oidx[b * S + j] = last;
        float bv0 = -1.f, bv1 = -1.f; int bi0 = 0, bi1 = 0;
        #pragma unroll
        for (int p = 0; p < P; p++) {
            float dx = px[p] - lx, dy = py[p] - ly, dz = pz[p] - lz;
            float d2 = __fadd_rn(__fadd_rn(__fmul_rn(dx, dx), __fmul_rn(dy, dy)), __fmul_rn(dz, dz));
            float d = fminf(dm[p], d2); dm[p] = d;
            if (p & 1) { if (d > bv1) { bv1 = d; bi1 = t * P + p; } }
            else       { if (d > bv0) { bv0 = d; bi0 = t * P + p; } }
        }
        float bestv = bv0; int besti = bi0;
        cmb(bestv, besti, bv1, bi1);
        cmb(bestv, besti, dppf<0xB1>(bestv),  dppi<0xB1>(besti));   // quad_perm [1,0,3,2]
        cmb(bestv, besti, dppf<0x4E>(bestv),  dppi<0x4E>(besti));   // quad_perm [2,3,0,1]
        cmb(bestv, besti, dppf<0x141>(bestv), dppi<0x141>(besti));  // row_half_mirror
        cmb(bestv, besti, dppf<0x140>(bestv), dppi<0x140>(besti));  // row_mirror
        cmb(bestv, besti, dppf<0x142>(bestv), dppi<0x142>(besti));  // row_bcast15
        cmb(bestv, besti, dppf<0x143>(bestv), dppi<0x143>(besti));  // row_bcast31
        int wbi = __builtin_amdgcn_readlane(besti, 63);
        unsigned wbu = (unsigned)__builtin_amdgcn_readlane((int)__float_as_uint(bestv), 63);
        int buf = j & 1;
        if (lane == 0) { rv[buf][wv] = __uint_as_float(wbu); ri[buf][wv] = wbi; }
        __syncthreads();
        int   i0 = ri[buf][0], i1 = ri[buf][1], i2 = ri[buf][2], i3 = ri[buf][3];
        float v0 = rv[buf][0], v1 = rv[buf][1], v2 = rv[buf][2], v3 = rv[buf][3];
        float x0 = sxx[i0], y0 = sxy[i0], z0 = sxz[i0];
        float x1 = sxx[i1], y1 = sxy[i1], z1 = sxz[i1];
        float x2 = sxx[i2], y2 = sxy[i2], z2 = sxz[i2];
        float x3 = sxx[i3], y3 = sxy[i3], z3 = sxz[i3];
        cmb5(v0, i0, x0, y0, z0, v1, i1, x1, y1, z1);
        cmb5(v2, i2, x2, y2, z2, v3, i3, x3, y3, z3);
        cmb5(v0, i0, x0, y0, z0, v2, i2, x2, y2, z2);
        last = i0;
        lx = x0; ly = y0; lz = z0;
    }
}

// ---------- FPS single-wave (small N): SoA + DPP reduce + readlane ----------
template<int P>
__global__ __launch_bounds__(64, 1) void fps_wave_kernel(
    const float* __restrict__ xyz, int N, int S, int* __restrict__ oidx)
{
    __shared__ float sxx[128], sxy[128], sxz[128];
    int b = blockIdx.x, lane = threadIdx.x;
    for (int i = lane; i < N; i += 64) {
        const float* p = xyz + ((size_t)b * N + i) * 3;
        sxx[i] = p[0]; sxy[i] = p[1]; sxz[i] = p[2];
    }
    __syncthreads();
    float px[P], py[P], pz[P], dm[P];
    #pragma unroll
    for (int p = 0; p < P; p++) {
        int i = lane * P + p;
        px[p] = sxx[i]; py[p] = sxy[i]; pz[p] = sxz[i];
        dm[p] = 1e10f;
    }
    int last = 0;
    float lx = sxx[0], ly = sxy[0], lz = sxz[0];
    for (int j = 0; j < S; j++) {
        if (lane == 0) oidx[b * S + j] = last;
        float bv0 = -1.f, bv1 = -1.f; int bi0 = 0, bi1 = 0;
        #pragma unroll
        for (int p = 0; p < P; p++) {
            float dx = px[p] - lx, dy = py[p] - ly, dz = pz[p] - lz;
            float d2 = __fadd_rn(__fadd_rn(__fmul_rn(dx, dx), __fmul_rn(dy, dy)), __fmul_rn(dz, dz));
            float d = fminf(dm[p], d2); dm[p] = d;
            if (p & 1) { if (d > bv1) { bv1 = d; bi1 = lane * P + p; } }
            else       { if (d > bv0) { bv0 = d; bi0 = lane * P + p; } }
        }
        float bestv = bv0; int besti = bi0;
        cmb(bestv, besti, bv1, bi1);
        cmb(bestv, besti, dppf<0xB1>(bestv),  dppi<0xB1>(besti));
        cmb(bestv, besti, dppf<0x4E>(bestv),  dppi<0x4E>(besti));
        cmb(bestv, besti, dppf<0x141>(bestv), dppi<0x141>(besti));
        cmb(bestv, besti, dppf<0x140>(bestv), dppi<0x140>(besti));
        cmb(bestv, besti, dppf<0x142>(bestv), dppi<0x142>(besti));  // row_bcast15
        cmb(bestv, besti, dppf<0x143>(bestv), dppi<0x143>(besti));  // row_bcast31
        last = __builtin_amdgcn_readlane(besti, 63);
        lx = sxx[last]; ly = sxy[last]; lz = sxz[last];
    }
}

// ---------- ball query ----------
__global__ __launch_bounds__(256) void ball_query_kernel(
    const float* __restrict__ xyz, const int* __restrict__ cidx,
    int N, int S, int nsample, float r2,
    int* __restrict__ nidx, float* __restrict__ newxyz)
{
    __shared__ float sx[1280 * 3];
    int b = blockIdx.x, t = threadIdx.x;
    for (int i = t; i < N * 3; i += 256) sx[i] = xyz[(size_t)b * N * 3 + i];
    __syncthreads();
    int w = t >> 6, lane = t & 63;
    int s = blockIdx.y * 4 + w;
    if (s >= S) return;
    int c = cidx[b * S + s];
    float cx = sx[c * 3], cy = sx[c * 3 + 1], cz = sx[c * 3 + 2];
    if (lane == 0) {
        newxyz[((size_t)b * S + s) * 3 + 0] = cx;
        newxyz[((size_t)b * S + s) * 3 + 1] = cy;
        newxyz[((size_t)b * S + s) * 3 + 2] = cz;
    }
    int P = N >> 6;
    int base = lane * P;
    unsigned mask = 0;
    for (int p = 0; p < P; p++) {
        int i = base + p;
        float dx = sx[i * 3] - cx, dy = sx[i * 3 + 1] - cy, dz = sx[i * 3 + 2] - cz;
        float d2 = __fadd_rn(__fadd_rn(__fmul_rn(dx, dx), __fmul_rn(dy, dy)), __fmul_rn(dz, dz));
        if (d2 < r2) mask |= (1u << p);
    }
    int cnt = __popc(mask);
    int pre = cnt;
    for (int off = 1; off < 64; off <<= 1) {
        int v = __shfl_up(pre, off, 64);
        if (lane >= off) pre += v;
    }
    int excl = pre - cnt;
    int total = __shfl(pre, 63, 64);
    size_t outb = ((size_t)b * S + s) * (size_t)nsample;
    unsigned mm = mask; int pos = excl;
    while (mm) {
        int p = __ffs(mm) - 1; mm &= mm - 1;
        if (pos < nsample) nidx[outb + pos] = base + p;
        pos++;
    }
    unsigned long long bal = __ballot(cnt > 0);
    int firstlane = __ffsll(bal) - 1;
    int firstidx = base + __ffs(mask) - 1;
    firstidx = __shfl(firstidx, firstlane, 64);
    for (int p = total + lane; p < nsample; p += 64) nidx[outb + p] = firstidx;
}

// =====================================================================
// SA1 layer-a stats via second moments (exact, replaces stats GEMM pass)
// =====================================================================
__global__ __launch_bounds__(256) void sa1_moment_kernel(
    const float* __restrict__ xyz, const int* __restrict__ nidx,
    const float* __restrict__ nx, float* __restrict__ mom)
{
    float a[35];
    #pragma unroll
    for (int i = 0; i < 35; i++) a[i] = 0.f;
    int gid = blockIdx.x * 256 + threadIdx.x;
    for (int ch = 0; ch < 8; ch++) {
        int r = ch * 65536 + gid;
        int n = nidx[r];
        int bs = r >> 6, b = r >> 13;
        const float* p = xyz + ((size_t)b * 1280 + n) * 3;
        float cx = nx[bs * 3], cy = nx[bs * 3 + 1], cz = nx[bs * 3 + 2];
        float x[7];
        x[0] = p[0] - cx; x[1] = p[1] - cy; x[2] = p[2] - cz;
        x[3] = p[0]; x[4] = p[1]; x[5] = p[2];
        x[6] = (n < 1024) ? 1.f : 0.f;
        #pragma unroll
        for (int k = 0; k < 7; k++) a[k] += x[k];
        int idx = 7;
        #pragma unroll
        for (int k = 0; k < 7; k++)
            #pragma unroll
            for (int l = k; l < 7; l++) { a[idx] = fmaf(x[k], x[l], a[idx]); idx++; }
    }
    #pragma unroll
    for (int off = 32; off > 0; off >>= 1)
        #pragma unroll
        for (int i = 0; i < 35; i++) a[i] += __shfl_xor(a[i], off, 64);
    __shared__ float red[4][35];
    int wv = threadIdx.x >> 6, lane = threadIdx.x & 63;
    if (lane == 0) {
        #pragma unroll
        for (int i = 0; i < 35; i++) red[wv][i] = a[i];
    }
    __syncthreads();
    int t = threadIdx.x;
    if (t < 35) atomicAdd(&mom[t], red[0][t] + red[1][t] + red[2][t] + red[3][t]);
}

__global__ __launch_bounds__(64) void sa1_mom_fin_kernel(
    const float* __restrict__ mom, const float* __restrict__ w1a,
    float* __restrict__ osum, float* __restrict__ osq)
{
    int n = threadIdx.x;
    float wn[7];
    #pragma unroll
    for (int k = 0; k < 7; k++) wn[k] = w1a[(size_t)k * 64 + n];
    float s = 0.f;
    #pragma unroll
    for (int k = 0; k < 7; k++) s = fmaf(mom[k], wn[k], s);
    float q = 0.f;
    int idx = 7;
    #pragma unroll
    for (int k = 0; k < 7; k++)
        #pragma unroll
        for (int l = k; l < 7; l++) {
            float w2 = wn[k] * wn[l];
            q = fmaf(mom[idx], (k == l) ? w2 : 2.f * w2, q);
            idx++;
        }
    osum[n] = s; osq[n] = q;
}

// ---- SA1 AB (fused): gather (vectorized, all-thread zero-fill), layer a, BN-a,
//      layer b (K=64), write Y(b raw) + stats ----
__global__ __launch_bounds__(256, 4) void sa1_ab_kernel(
    const float* __restrict__ xyz, const int* __restrict__ nidx,
    const float* __restrict__ nx,
    const unsigned short* __restrict__ W1h, const unsigned short* __restrict__ W1l,
    const unsigned short* __restrict__ W2h, const unsigned short* __restrict__ W2l,
    const float* __restrict__ s1, const float* __restrict__ q1,
    const float* __restrict__ g1, const float* __restrict__ b1,
    float* __restrict__ ps, float* __restrict__ pq, float* __restrict__ Y)
{
    __shared__ unsigned short Xhi[64 * 40], Xlo[64 * 40];
    __shared__ unsigned short Hh[64 * 72], Hl[64 * 72];
    __shared__ float aA[64], aB[64];
    __shared__ float cs[64], cq[64];
    const float IR = 1.f / 524288.f;
    int bs = blockIdx.x, b = bs >> 7, t = threadIdx.x;
    // zero-fill k=8..39 spread over all 256 threads (2 vector stores each)
    {
        int r = t >> 2, qd = t & 3;
        s16x8 z = {0, 0, 0, 0, 0, 0, 0, 0};
        *(s16x8*)&Xhi[r * 40 + 8 + qd * 8] = z;
        *(s16x8*)&Xlo[r * 40 + 8 + qd * 8] = z;
    }
    if (t < 64) {
        float mu = s1[t] * IR;
        float rs = rsqrtf(q1[t] * IR - mu * mu + BN_EPS);
        float a = rs * g1[t];
        aA[t] = a; aB[t] = b1[t] - mu * a;
        int n = nidx[(size_t)bs * 64 + t];
        const float* p = xyz + ((size_t)b * 1280 + n) * 3;
        float cx = nx[bs * 3], cy = nx[bs * 3 + 1], cz = nx[bs * 3 + 2];
        float v[7] = { p[0] - cx, p[1] - cy, p[2] - cz, p[0], p[1], p[2], (n < 1024) ? 1.f : 0.f };
        s16x8 vh, vl;
        #pragma unroll
        for (int k = 0; k < 7; k++) {
            unsigned short hi = f2b(v[k]);
            vh[k] = (short)hi;
            vl[k] = (short)f2b(v[k] - b2f(hi));
        }
        vh[7] = 0; vl[7] = 0;
        *(s16x8*)&Xhi[t * 40] = vh;
        *(s16x8*)&Xlo[t * 40] = vl;
    }
    __syncthreads();
    int wv = t >> 6, lane = t & 63;
    int quad = lane >> 4, l16 = lane & 15;
    int aoff = quad * 8;

    // layer a (12 MFMA)
    f32x4v acc[4] = {};
    {
        size_t woff = (size_t)(wv * 16 + l16) * 32 + aoff;
        s16x8 bh = *(const s16x8*)(W1h + woff);
        s16x8 bl = *(const s16x8*)(W1l + woff);
        #pragma unroll
        for (int mt = 0; mt < 4; mt++) {
            s16x8 ah = *(const s16x8*)&Xhi[(mt * 16 + l16) * 40 + aoff];
            s16x8 al = *(const s16x8*)&Xlo[(mt * 16 + l16) * 40 + aoff];
            acc[mt] = MFMA_B16(al, bh, acc[mt]);
            acc[mt] = MFMA_B16(ah, bl, acc[mt]);
            acc[mt] = MFMA_B16(ah, bh, acc[mt]);
        }
    }
    // BN-a + ReLU -> Hh/Hl (split bf16)
    {
        int n = wv * 16 + l16;
        float a = aA[n], bb = aB[n];
        #pragma unroll
        for (int mt = 0; mt < 4; mt++)
            #pragma unroll
            for (int r = 0; r < 4; r++) {
                int m = mt * 16 + quad * 4 + r;
                float h = fmaxf(acc[mt][r] * a + bb, 0.f);
                unsigned short hi = f2b(h);
                Hh[m * 72 + n] = hi;
                Hl[m * 72 + n] = f2b(h - b2f(hi));
            }
    }
    __syncthreads();

    // layer b (24 MFMA), write Y + stats
    f32x4v ac2[4] = {};
    #pragma unroll
    for (int kc = 0; kc < 64; kc += 32) {
        size_t woff = (size_t)(wv * 16 + l16) * 64 + kc + aoff;
        s16x8 bh = *(const s16x8*)(W2h + woff);
        s16x8 bl = *(const s16x8*)(W2l + woff);
        #pragma unroll
        for (int mt = 0; mt < 4; mt++) {
            s16x8 ah = *(const s16x8*)&Hh[(mt * 16 + l16) * 72 + kc + aoff];
            s16x8 al = *(const s16x8*)&Hl[(mt * 16 + l16) * 72 + kc + aoff];
            ac2[mt] = MFMA_B16(al, bh, ac2[mt]);
            ac2[mt] = MFMA_B16(ah, bl, ac2[mt]);
            ac2[mt] = MFMA_B16(ah, bh, ac2[mt]);
        }
    }
    int n = wv * 16 + l16;
    float s = 0.f, q = 0.f;
    #pragma unroll
    for (int mt = 0; mt < 4; mt++)
        #pragma unroll
        for (int r = 0; r < 4; r++) {
            int m = mt * 16 + quad * 4 + r;
            float v = ac2[mt][r];
            Y[((size_t)bs * 64 + m) * 64 + n] = v;
            s += v; q += v * v;
        }
    s += __shfl_xor(s, 16, 64); q += __shfl_xor(q, 16, 64);
    s += __shfl_xor(s, 32, 64); q += __shfl_xor(q, 32, 64);
    if (quad == 0) { cs[n] = s; cq[n] = q; }
    __syncthreads();
    if (t < 64) { ps[(size_t)bs * 64 + t] = cs[t]; pq[(size_t)bs * 64 + t] = cq[t]; }
}

// ---- SA1 C: 8 waves (512 thr), 2 groups/block, BN-b + layer c (128x128, K=64) ----
__global__ __launch_bounds__(512, 4) void sa1_c_kernel(
    const float* __restrict__ Y,
    const unsigned short* __restrict__ Wh, const unsigned short* __restrict__ Wl,
    const float* __restrict__ s2, const float* __restrict__ q2,
    const float* __restrict__ g2, const float* __restrict__ b2,
    float* __restrict__ ps, float* __restrict__ pq,
    float* __restrict__ pmax, float* __restrict__ pmin)
{
    __shared__ unsigned short Xhi[128 * 72], Xlo[128 * 72];
    __shared__ float aA[64], aB[64];
    __shared__ float cs2[2][128], cq2[2][128];
    __shared__ float cmx[2][128], cmn[2][128];
    const float IR = 1.f / 524288.f;
    int bs0 = blockIdx.x * 2;
    size_t rbase = (size_t)blockIdx.x * 128;
    int t = threadIdx.x;
    if (t < 64) {
        float mu = s2[t] * IR;
        float rs = rsqrtf(q2[t] * IR - mu * mu + BN_EPS);
        float a = rs * g2[t];
        aA[t] = a; aB[t] = b2[t] - mu * a;
    }
    __syncthreads();
    {
        int r = t >> 2, seg = t & 3;
        const float4* y4 = (const float4*)(Y + (rbase + r) * 64 + seg * 16);
        float4 v[4];
        #pragma unroll
        for (int i = 0; i < 4; i++) v[i] = y4[i];
        s16x8 ph[2], pl[2];
        #pragma unroll
        for (int i = 0; i < 4; i++) {
            #pragma unroll
            for (int j = 0; j < 4; j++) {
                int e = i * 4 + j;
                int c = seg * 16 + e;
                float x = fmaxf(((const float*)&v[i])[j] * aA[c] + aB[c], 0.f);
                unsigned short hi = f2b(x);
                ph[e >> 3][e & 7] = (short)hi;
                pl[e >> 3][e & 7] = (short)f2b(x - b2f(hi));
            }
        }
        #pragma unroll
        for (int k = 0; k < 2; k++) {
            *(s16x8*)&Xhi[r * 72 + seg * 16 + k * 8] = ph[k];
            *(s16x8*)&Xlo[r * 72 + seg * 16 + k * 8] = pl[k];
        }
    }
    __syncthreads();
    int wv = t >> 6, lane = t & 63;
    int wh = wv >> 2, wc = wv & 3;
    int quad = lane >> 4, l16 = lane & 15;
    int aoff = quad * 8;

    f32x4v a3[4][2] = {};
    #pragma unroll
    for (int kc = 0; kc < 64; kc += 32) {
        s16x8 ah[4], al[4];
        #pragma unroll
        for (int mi = 0; mi < 4; mi++) {
            int mt = wh * 4 + mi;
            ah[mi] = *(const s16x8*)&Xhi[(mt * 16 + l16) * 72 + kc + aoff];
            al[mi] = *(const s16x8*)&Xlo[(mt * 16 + l16) * 72 + kc + aoff];
        }
        #pragma unroll
        for (int nt = 0; nt < 2; nt++) {
            size_t woff = (size_t)(wc * 32 + nt * 16 + l16) * 64 + kc + aoff;
            s16x8 bh = *(const s16x8*)(Wh + woff);
            s16x8 bl = *(const s16x8*)(Wl + woff);
            #pragma unroll
            for (int mi = 0; mi < 4; mi++) {
                a3[mi][nt] = MFMA_B16(al[mi], bh, a3[mi][nt]);
                a3[mi][nt] = MFMA_B16(ah[mi], bl, a3[mi][nt]);
                a3[mi][nt] = MFMA_B16(ah[mi], bh, a3[mi][nt]);
            }
        }
    }
    #pragma unroll
    for (int nt = 0; nt < 2; nt++) {
        int n = wc * 32 + nt * 16 + l16;
        float s = 0.f, q = 0.f, mx = -3.4e38f, mn_ = 3.4e38f;
        #pragma unroll
        for (int mi = 0; mi < 4; mi++)
            #pragma unroll
            for (int r = 0; r < 4; r++) {
                float v = a3[mi][nt][r]; s += v; q += v * v;
                mx = fmaxf(mx, v); mn_ = fminf(mn_, v);
            }
        s += __shfl_xor(s, 16, 64); q += __shfl_xor(q, 16, 64);
        mx = fmaxf(mx, __shfl_xor(mx, 16, 64)); mn_ = fminf(mn_, __shfl_xor(mn_, 16, 64));
        s += __shfl_xor(s, 32, 64); q += __shfl_xor(q, 32, 64);
        mx = fmaxf(mx, __shfl_xor(mx, 32, 64)); mn_ = fminf(mn_, __shfl_xor(mn_, 32, 64));
        if (quad == 0) {
            cs2[wh][n] = s; cq2[wh][n] = q;
            cmx[wh][n] = mx; cmn[wh][n] = mn_;
        }
    }
    __syncthreads();
    if (t < 128) {
        ps[(size_t)blockIdx.x * 128 + t] = cs2[0][t] + cs2[1][t];
        pq[(size_t)blockIdx.x * 128 + t] = cq2[0][t] + cq2[1][t];
        pmax[(size_t)(bs0 + 0) * 128 + t] = cmx[0][t];
        pmin[(size_t)(bs0 + 0) * 128 + t] = cmn[0][t];
        pmax[(size_t)(bs0 + 1) * 128 + t] = cmx[1][t];
        pmin[(size_t)(bs0 + 1) * 128 + t] = cmn[1][t];
    }
}

// ---------- finalize SA1 pool -> BN+ReLU feature map FE1 (4 MB) ----------
__global__ __launch_bounds__(256) void bnpool_fin_kernel(
    const float* __restrict__ pmax, const float* __restrict__ pmin,
    const float* __restrict__ sum, const float* __restrict__ sq,
    const float* __restrict__ g, const float* __restrict__ bb,
    float rcnt, float* __restrict__ out, int total, int dmask)
{
    int i = blockIdx.x * 256 + threadIdx.x;
    if (i >= total) return;
    int d = i & dmask;
    float mu = sum[d] * rcnt;
    float rs = rsqrtf(sq[d] * rcnt - mu * mu + BN_EPS);
    float gv = g[d];
    float v = (gv >= 0.f) ? pmax[i] : pmin[i];
    out[i] = fmaxf((v - mu) * rs * gv + bb[d], 0.f);
}

// ---- SA2 A: 8 waves (512 thr), 64 rows/block, gather FE1, layer a (K=160) ----
__global__ __launch_bounds__(512, 4) void sa2_a_kernel(
    const float* __restrict__ xyz1, const int* __restrict__ nidx2,
    const float* __restrict__ nx2, const float* __restrict__ feat1,
    const unsigned short* __restrict__ Wh, const unsigned short* __restrict__ Wl,
    float* __restrict__ ps, float* __restrict__ pq, float* __restrict__ Y)
{
    __shared__ unsigned short Xhi[64 * 168], Xlo[64 * 168];
    __shared__ float cs[128], cq[128];
    __shared__ int sn[64];
    int row0 = blockIdx.x * 64;
    int bs = row0 >> 7, b = bs >> 5;
    int t = threadIdx.x;
    if (t < 64) sn[t] = nidx2[(size_t)bs * 128 + (row0 & 127) + t];
    __syncthreads();
    {
        int r = t >> 3, seg = t & 7;
        int n = sn[r];
        size_t base = ((size_t)(b * 128 + n)) * 128 + seg * 16;
        const float4* fr = (const float4*)(feat1 + base);
        float4 v[4];
        #pragma unroll
        for (int i = 0; i < 4; i++) v[i] = fr[i];
        s16x8 ph[2], pl[2];
        #pragma unroll
        for (int i = 0; i < 4; i++) {
            #pragma unroll
            for (int j = 0; j < 4; j++) {
                int e = i * 4 + j;
                float x = ((const float*)&v[i])[j];
                unsigned short hi = f2b(x);
                ph[e >> 3][e & 7] = (short)hi;
                pl[e >> 3][e & 7] = (short)f2b(x - b2f(hi));
            }
        }
        #pragma unroll
        for (int k = 0; k < 2; k++) {
            *(s16x8*)&Xhi[r * 168 + seg * 16 + k * 8] = ph[k];
            *(s16x8*)&Xlo[r * 168 + seg * 16 + k * 8] = pl[k];
        }
        if (seg == 0) {
            float c3x = nx2[bs * 3], c3y = nx2[bs * 3 + 1], c3z = nx2[bs * 3 + 2];
            const float* pz = xyz1 + ((size_t)b * 128 + n) * 3;
            float g3[3] = { pz[0] - c3x, pz[1] - c3y, pz[2] - c3z };
            s16x8 th = {0, 0, 0, 0, 0, 0, 0, 0}, tl = {0, 0, 0, 0, 0, 0, 0, 0};
            #pragma unroll
            for (int i = 0; i < 3; i++) {
                unsigned short hi = f2b(g3[i]);
                th[i] = (short)hi;
                tl[i] = (short)f2b(g3[i] - b2f(hi));
            }
            *(s16x8*)&Xhi[r * 168 + 128] = th;
            *(s16x8*)&Xlo[r * 168 + 128] = tl;
            s16x8 z = {0, 0, 0, 0, 0, 0, 0, 0};
            #pragma unroll
            for (int k = 0; k < 4; k++) {
                *(s16x8*)&Xhi[r * 168 + 136 + k * 8] = z;
                *(s16x8*)&Xlo[r * 168 + 136 + k * 8] = z;
            }
        }
    }
    __syncthreads();
    int wv = t >> 6, lane = t & 63;
    int quad = lane >> 4, l16 = lane & 15;
    int aoff = quad * 8;

    f32x4v acc[4] = {};
    #pragma unroll
    for (int kc = 0; kc < 160; kc += 32) {
        s16x8 ah[4], al[4];
        #pragma unroll
        for (int mt = 0; mt < 4; mt++) {
            ah[mt] = *(const s16x8*)&Xhi[(mt * 16 + l16) * 168 + kc + aoff];
            al[mt] = *(const s16x8*)&Xlo[(mt * 16 + l16) * 168 + kc + aoff];
        }
        size_t woff = (size_t)(wv * 16 + l16) * 160 + kc + aoff;
        s16x8 bh = *(const s16x8*)(Wh + woff);
        s16x8 bl = *(const s16x8*)(Wl + woff);
        #pragma unroll
        for (int mt = 0; mt < 4; mt++) {
            acc[mt] = MFMA_B16(al[mt], bh, acc[mt]);
            acc[mt] = MFMA_B16(ah[mt], bl, acc[mt]);
            acc[mt] = MFMA_B16(ah[mt], bh, acc[mt]);
        }
    }
    {
        int n = wv * 16 + l16;
        float s = 0.f, q = 0.f;
        #pragma unroll
        for (int mt = 0; mt < 4; mt++)
            #pragma unroll
            for (int r = 0; r < 4; r++) {
                int m = mt * 16 + quad * 4 + r;
                float v = acc[mt][r];
                Y[((size_t)row0 + m) * 128 + n] = v;
                s += v; q += v * v;
            }
        s += __shfl_xor(s, 16, 64); q += __shfl_xor(q, 16, 64);
        s += __shfl_xor(s, 32, 64); q += __shfl_xor(q, 32, 64);
        if (quad == 0) { cs[n] = s; cq[n] = q; }
    }
    __syncthreads();
    if (t < 128) { ps[(size_t)blockIdx.x * 128 + t] = cs[t]; pq[(size_t)blockIdx.x * 128 + t] = cq[t]; }
}

// ---- SA2 B: 8 waves (512 thr), 64 rows/block, BN-a + layer b (K=128), Y in place ----
__global__ __launch_bounds__(512, 4) void sa2_b_kernel(
    float* __restrict__ Y,
    const unsigned short* __restrict__ Wh, const unsigned short* __restrict__ Wl,
    const float* __restrict__ s1, const float* __restrict__ q1,
    const float* __restrict__ g1, const float* __restrict__ b1,
    float* __restrict__ ps, float* __restrict__ pq)
{
    __shared__ unsigned short Xhi[64 * 136], Xlo[64 * 136];
    __shared__ float aA[128], aB[128];
    __shared__ float cs[128], cq[128];
    const float IR = 1.f / 262144.f;
    int row0 = blockIdx.x * 64;
    int t = threadIdx.x;
    if (t < 128) {
        float mu = s1[t] * IR;
        float rs = rsqrtf(q1[t] * IR - mu * mu + BN_EPS);
        float a = rs * g1[t];
        aA[t] = a; aB[t] = b1[t] - mu * a;
    }
    __syncthreads();
    {
        int r = t >> 3, seg = t & 7;
        const float4* y4 = (const float4*)(Y + ((size_t)row0 + r) * 128 + seg * 16);
        float4 v[4];
        #pragma unroll
        for (int i = 0; i < 4; i++) v[i] = y4[i];
        s16x8 ph[2], pl[2];
        #pragma unroll
        for (int i = 0; i < 4; i++) {
            #pragma unroll
            for (int j = 0; j < 4; j++) {
                int e = i * 4 + j;
                int c = seg * 16 + e;
                float x = fmaxf(((const float*)&v[i])[j] * aA[c] + aB[c], 0.f);
                unsigned short hi = f2b(x);
                ph[e >> 3][e & 7] = (short)hi;
                pl[e >> 3][e & 7] = (short)f2b(x - b2f(hi));
            }
        }
        #pragma unroll
        for (int k = 0; k < 2; k++) {
            *(s16x8*)&Xhi[r * 136 + seg * 16 + k * 8] = ph[k];
            *(s16x8*)&Xlo[r * 136 + seg * 16 + k * 8] = pl[k];
        }
    }
    __syncthreads();
    int wv = t >> 6, lane = t & 63;
    int quad = lane >> 4, l16 = lane & 15;
    int aoff = quad * 8;

    f32x4v ac2[4] = {};
    #pragma unroll
    for (int kc = 0; kc < 128; kc += 32) {
        s16x8 ah[4], al[4];
        #pragma unroll
        for (int mt = 0; mt < 4; mt++) {
            ah[mt] = *(const s16x8*)&Xhi[(mt * 16 + l16) * 136 + kc + aoff];
            al[mt] = *(const s16x8*)&Xlo[(mt * 16 + l16) * 136 + kc + aoff];
        }
        size_t woff = (size_t)(wv * 16 + l16) * 128 + kc + aoff;
        s16x8 bh = *(const s16x8*)(Wh + woff);
        s16x8 bl = *(const s16x8*)(Wl + woff);
        #pragma unroll
        for (int mt = 0; mt < 4; mt++) {
            ac2[mt] = MFMA_B16(al[mt], bh, ac2[mt]);
            ac2[mt] = MFMA_B16(ah[mt], bl, ac2[mt]);
            ac2[mt] = MFMA_B16(ah[mt], bh, ac2[mt]);
        }
    }
    {
        int n = wv * 16 + l16;
        float s = 0.f, q = 0.f;
        #pragma unroll
        for (int mt = 0; mt < 4; mt++)
            #pragma unroll
            for (int r = 0; r < 4; r++) {
                int m = mt * 16 + quad * 4 + r;
                float v = ac2[mt][r];
                Y[((size_t)row0 + m) * 128 + n] = v;
                s += v; q += v * v;
            }
        s += __shfl_xor(s, 16, 64); q += __shfl_xor(q, 16, 64);
        s += __shfl_xor(s, 32, 64); q += __shfl_xor(q, 32, 64);
        if (quad == 0) { cs[n] = s; cq[n] = q; }
    }
    __syncthreads();
    if (t < 128) { ps[(size_t)blockIdx.x * 128 + t] = cs[t]; pq[(size_t)blockIdx.x * 128 + t] = cq[t]; }
}

// ---- SA2 C: 8 waves (512 thr), 64 rows/block, BN-b + layer c (64x256, K=128) ----
__global__ __launch_bounds__(512, 4) void sa2_c_kernel(
    const float* __restrict__ Y,
    const unsigned short* __restrict__ Wh, const unsigned short* __restrict__ Wl,
    const float* __restrict__ s2, const float* __restrict__ q2,
    const float* __restrict__ g2, const float* __restrict__ b2,
    float* __restrict__ ps, float* __restrict__ pq,
    unsigned* __restrict__ pmax, unsigned* __restrict__ pmin)
{
    __shared__ unsigned short Xhi[64 * 136], Xlo[64 * 136];
    __shared__ float aA[128], aB[128];
    __shared__ float cs[256], cq[256];
    __shared__ float cmx[256], cmn[256];
    const float IR = 1.f / 262144.f;
    int row0 = blockIdx.x * 64;
    int bs = row0 >> 7;
    int t = threadIdx.x;
    if (t < 128) {
        float mu = s2[t] * IR;
        float rs = rsqrtf(q2[t] * IR - mu * mu + BN_EPS);
        float a = rs * g2[t];
        aA[t] = a; aB[t] = b2[t] - mu * a;
    }
    __syncthreads();
    {
        int r = t >> 3, seg = t & 7;
        const float4* y4 = (const float4*)(Y + ((size_t)row0 + r) * 128 + seg * 16);
        float4 v[4];
        #pragma unroll
        for (int i = 0; i < 4; i++) v[i] = y4[i];
        s16x8 ph[2], pl[2];
        #pragma unroll
        for (int i = 0; i < 4; i++) {
            #pragma unroll
            for (int j = 0; j < 4; j++) {
                int e = i * 4 + j;
                int c = seg * 16 + e;
                float x = fmaxf(((const float*)&v[i])[j] * aA[c] + aB[c], 0.f);
                unsigned short hi = f2b(x);
                ph[e >> 3][e & 7] = (short)hi;
                pl[e >> 3][e & 7] = (short)f2b(x - b2f(hi));
            }
        }
        #pragma unroll
        for (int k = 0; k < 2; k++) {
            *(s16x8*)&Xhi[r * 136 + seg * 16 + k * 8] = ph[k];
            *(s16x8*)&Xlo[r * 136 + seg * 16 + k * 8] = pl[k];
        }
    }
    __syncthreads();
    int wv = t >> 6, lane = t & 63;
    int quad = lane >> 4, l16 = lane & 15;
    int aoff = quad * 8;

    f32x4v a3[4][2] = {};
    #pragma unroll
    for (int kc = 0; kc < 128; kc += 32) {
        s16x8 ah[4], al[4];
        #pragma unroll
        for (int mt = 0; mt < 4; mt++) {
            ah[mt] = *(const s16x8*)&Xhi[(mt * 16 + l16) * 136 + kc + aoff];
            al[mt] = *(const s16x8*)&Xlo[(mt * 16 + l16) * 136 + kc + aoff];
        }
        #pragma unroll
        for (int ct = 0; ct < 2; ct++) {
            size_t woff = (size_t)(wv * 32 + ct * 16 + l16) * 128 + kc + aoff;
            s16x8 bh = *(const s16x8*)(Wh + woff);
            s16x8 bl = *(const s16x8*)(Wl + woff);
            #pragma unroll
            for (int mt = 0; mt < 4; mt++) {
                a3[mt][ct] = MFMA_B16(al[mt], bh, a3[mt][ct]);
                a3[mt][ct] = MFMA_B16(ah[mt], bl, a3[mt][ct]);
                a3[mt][ct] = MFMA_B16(ah[mt], bh, a3[mt][ct]);
            }
        }
    }
    #pragma unroll
    for (int ct = 0; ct < 2; ct++) {
        int n = wv * 32 + ct * 16 + l16;
        float s = 0.f, q = 0.f, mx = -3.4e38f, mn = 3.4e38f;
        #pragma unroll
        for (int mt = 0; mt < 4; mt++)
            #pragma unroll
            for (int r = 0; r < 4; r++) {
                float v = a3[mt][ct][r]; s += v; q += v * v;
                mx = fmaxf(mx, v); mn = fminf(mn, v);
            }
        s += __shfl_xor(s, 16, 64); q += __shfl_xor(q, 16, 64);
        mx = fmaxf(mx, __shfl_xor(mx, 16, 64)); mn = fminf(mn, __shfl_xor(mn, 16, 64));
        s += __shfl_xor(s, 32, 64); q += __shfl_xor(q, 32, 64);
        mx = fmaxf(mx, __shfl_xor(mx, 32, 64)); mn = fminf(mn, __shfl_xor(mn, 32, 64));
        if (quad == 0) { cs[n] = s; cq[n] = q; cmx[n] = mx; cmn[n] = mn; }
    }
    __syncthreads();
    if (t < 256) {
        ps[(size_t)blockIdx.x * 256 + t] = cs[t]; pq[(size_t)blockIdx.x * 256 + t] = cq[t];
        atomicMax(&pmax[(size_t)bs * 256 + t], fenc(cmx[t]));
        atomicMin(&pmin[(size_t)bs * 256 + t], fenc(cmn[t]));
    }
}

// ---------- build SA3 input (2048 x 259) ----------
__global__ __launch_bounds__(256) void grouped3_prep_kernel(
    const float* __restrict__ nx2, const unsigned* __restrict__ pmax,
    const unsigned* __restrict__ pmin, const float* __restrict__ sum,
    const float* __restrict__ sq, const float* __restrict__ g,
    const float* __restrict__ bb, float rcnt, float* __restrict__ out)
{
    int row = blockIdx.x;
    int t = threadIdx.x;
    for (int c = t; c < 259; c += 256) {
        float v;
        if (c < 3) v = nx2[row * 3 + c];
        else {
            int d = c - 3;
            float mu = sum[d] * rcnt;
            float rs = rsqrtf(sq[d] * rcnt - mu * mu + BN_EPS);
            float gv = g[d];
            float x = fdec((gv >= 0.f) ? pmax[(size_t)row * 256 + d] : pmin[(size_t)row * 256 + d]);
            v = fmaxf((x - mu) * rs * gv + bb[d], 0.f);
        }
        out[(size_t)row * 259 + c] = v;
    }
}

// ---------- generic GEMM (SA3) ----------
__global__ __launch_bounds__(256) void gemm_bn_kernel(
    const float* __restrict__ X, const float* __restrict__ W,
    const float* __restrict__ bias, float* __restrict__ Y,
    const float* __restrict__ isum, const float* __restrict__ isq,
    const float* __restrict__ ig, const float* __restrict__ ib, float ircnt,
    float* __restrict__ osum, float* __restrict__ osq,
    int M, int C, int D)
{
    __shared__ float Xs[64 * 33];
    __shared__ float Ws[32 * 64];
    __shared__ float cs[64], cq[64];
    int m0 = blockIdx.x * 64;
    int d0 = blockIdx.y * 64;
    int t = threadIdx.x;
    int tr = t >> 4, tc = t & 15, r0 = tr * 4, c0 = tc * 4;
    float acc[4][4] = {};
    int nchunk = (C + 31) / 32;
    for (int ch = 0; ch < nchunk; ch++) {
        int kbase = ch * 32;
        for (int f = t; f < 64 * 32; f += 256) {
            int r = f >> 5, c = f & 31; int gc = kbase + c;
            float v = 0.f;
            if (gc < C) {
                v = X[(size_t)(m0 + r) * C + gc];
                if (isum) {
                    float mu = isum[gc] * ircnt;
                    float rs = rsqrtf(isq[gc] * ircnt - mu * mu + BN_EPS);
                    v = fmaxf((v - mu) * rs * ig[gc] + ib[gc], 0.f);
                }
            }
            Xs[r * 33 + c] = v;
        }
        for (int f = t; f < 32 * 64; f += 256) {
            int c = f >> 6, j = f & 63; int gc = kbase + c;
            Ws[f] = (gc < C) ? W[(size_t)gc * D + d0 + j] : 0.f;
        }
        __syncthreads();
        #pragma unroll 8
        for (int kk = 0; kk < 32; kk++) {
            float xv[4], wv[4];
            #pragma unroll
            for (int i = 0; i < 4; i++) xv[i] = Xs[(r0 + i) * 33 + kk];
            #pragma unroll
            for (int j = 0; j < 4; j++) wv[j] = Ws[kk * 64 + c0 + j];
            #pragma unroll
            for (int i = 0; i < 4; i++)
                #pragma unroll
                for (int j = 0; j < 4; j++)
                    acc[i][j] = fmaf(xv[i], wv[j], acc[i][j]);
        }
        __syncthreads();
    }
    if (bias) {
        #pragma unroll
        for (int j = 0; j < 4; j++) {
            float bv = bias[d0 + c0 + j];
            #pragma unroll
            for (int i = 0; i < 4; i++) acc[i][j] += bv;
        }
    }
    #pragma unroll
    for (int i = 0; i < 4; i++) {
        float4 v = make_float4(acc[i][0], acc[i][1], acc[i][2], acc[i][3]);
        *(float4*)(Y + (size_t)(m0 + r0 + i) * D + d0 + c0) = v;
    }
    if (t < 64) { cs[t] = 0.f; cq[t] = 0.f; }
    __syncthreads();
    #pragma unroll
    for (int j = 0; j < 4; j++) {
        int col = c0 + j;
        float s = 0.f, q = 0.f;
        #pragma unroll
        for (int i = 0; i < 4; i++) { float v = acc[i][j]; s += v; q += v * v; }
        atomicAdd(&cs[col], s); atomicAdd(&cq[col], q);
    }
    __syncthreads();
    if (t < 64) { atomicAdd(&osum[d0 + t], cs[t]); atomicAdd(&osq[d0 + t], cq[t]); }
}

// ---------- FC split-K GEMM ----------
__global__ __launch_bounds__(256) void fc_gemm_kernel(
    const float* __restrict__ X, const float* __restrict__ W,
    const float* __restrict__ isum, const float* __restrict__ isq,
    const float* __restrict__ ig, const float* __restrict__ ib, float ircnt,
    float* __restrict__ PP, int C, int D)
{
    __shared__ float Xs[64 * 132];
    int d0 = blockIdx.x * 64;
    int KS = gridDim.y;
    int L = C / KS;
    int kbase = blockIdx.y * L;
    int t = threadIdx.x;
    for (int f = t; f < 64 * L; f += 256) {
        int r = f / L, k = f - r * L;
        int gc = kbase + k;
        float v = X[(size_t)r * C + gc];
        if (isum) {
            float mu = isum[gc] * ircnt;
            float rs = rsqrtf(isq[gc] * ircnt - mu * mu + BN_EPS);
            v = fmaxf((v - mu) * rs * ig[gc] + ib[gc], 0.f);
        }
        Xs[r * 132 + k] = v;
    }
    __syncthreads();
    int tr = t >> 4, tc = t & 15, r0 = tr * 4, c0 = tc * 4;
    float acc[4][4] = {};
    for (int k = 0; k < L; k++) {
        float xv[4];
        #pragma unroll
        for (int i = 0; i < 4; i++) xv[i] = Xs[(r0 + i) * 132 + k];
        float4 wv = *(const float4*)(W + (size_t)(kbase + k) * D + d0 + c0);
        #pragma unroll
        for (int i = 0; i < 4; i++) {
            acc[i][0] = fmaf(xv[i], wv.x, acc[i][0]);
            acc[i][1] = fmaf(xv[i], wv.y, acc[i][1]);
            acc[i][2] = fmaf(xv[i], wv.z, acc[i][2]);
            acc[i][3] = fmaf(xv[i], wv.w, acc[i][3]);
        }
    }
    float* pp = PP + (size_t)blockIdx.y * 64 * D;
    #pragma unroll
    for (int i = 0; i < 4; i++) {
        float4 v = make_float4(acc[i][0], acc[i][1], acc[i][2], acc[i][3]);
        *(float4*)(pp + (size_t)(r0 + i) * D + d0 + c0) = v;
    }
}

// ---------- FC finalize + fused column stats (osum/osq pre-zeroed) ----------
__global__ __launch_bounds__(256) void fc_fin_kernel(
    const float* __restrict__ PP, const float* __restrict__ bias,
    int D, int KS, float* __restrict__ Y,
    float* __restrict__ osum, float* __restrict__ osq)
{
    int i = blockIdx.x * 256 + threadIdx.x;
    if (i >= 64 * D) return;
    int n = i % D;
    float s = 0.f;
    for (int k = 0; k < KS; k++) s += PP[(size_t)k * 64 * D + i];
    float y = s + bias[n];
    Y[i] = y;
    atomicAdd(&osum[n], y);
    atomicAdd(&osq[n], y * y);
}

// ---------- SA3 pool ----------
__global__ __launch_bounds__(256) void pool3_kernel(
    const float* __restrict__ h, const float* __restrict__ sum,
    const float* __restrict__ sq, const float* __restrict__ g,
    const float* __restrict__ bb, float* __restrict__ out)
{
    int i = blockIdx.x * 256 + threadIdx.x;
    if (i >= 32768) return;
    int d = i & 511, b = i >> 9;
    const float rcnt = 1.f / 2048.f;
    float mu = sum[d] * rcnt;
    float rs = rsqrtf(sq[d] * rcnt - mu * mu + BN_EPS);
    float gv = g[d], bv = bb[d];
    float m = -3.4e38f;
    for (int k = 0; k < 32; k++) {
        float v = h[((size_t)b * 32 + k) * 512 + d];
        m = fmaxf(m, fmaxf((v - mu) * rs * gv + bv, 0.f));
    }
    out[i] = m;
}

// ---------- head ----------
__global__ __launch_bounds__(256) void head_kernel(
    const float* __restrict__ y2, const float* __restrict__ sum,
    const float* __restrict__ sq, const float* __restrict__ g,
    const float* __restrict__ bb, const float* __restrict__ hw,
    const float* __restrict__ hb, float* __restrict__ out)
{
    __shared__ float red[256];
    int b = blockIdx.x, t = threadIdx.x;
    const float rcnt = 1.f / 64.f;
    float part = 0.f;
    for (int d = t; d < 1024; d += 256) {
        float mu = sum[d] * rcnt;
        float rs = rsqrtf(sq[d] * rcnt - mu * mu + BN_EPS);
        float v = fmaxf((y2[(size_t)b * 1024 + d] - mu) * rs * g[d] + bb[d], 0.f);
        part = fmaf(v, hw[d], part);
    }
    red[t] = part; __syncthreads();
    if (t < 128) red[t] += red[t + 128];
    __syncthreads();
    if (t < 64) {
        float v = red[t] + red[t + 64];
        for (int off = 32; off > 0; off >>= 1) v += __shfl_down(v, off, 64);
        if (t == 0) out[b] = v + hb[0];
    }
}

extern "C" void kernel_launch(void* const* d_in, const int* in_sizes, int n_in,
                              void* d_out, int out_size, void* d_ws, size_t ws_size,
                              hipStream_t stream)
{
    (void)in_sizes; (void)n_in; (void)out_size; (void)ws_size;
    const float* pc  = (const float*)d_in[0];
    const float* gpc = (const float*)d_in[1];
    const float* w1a = (const float*)d_in[2];  const float* g1a = (const float*)d_in[3];  const float* b1a = (const float*)d_in[4];
    const float* w1b = (const float*)d_in[5];  const float* g1b = (const float*)d_in[6];  const float* b1b = (const float*)d_in[7];
    const float* w1c = (const float*)d_in[8];  const float* g1c = (const float*)d_in[9];  const float* b1c = (const float*)d_in[10];
    const float* w2a = (const float*)d_in[11]; const float* g2a = (const float*)d_in[12]; const float* b2a = (const float*)d_in[13];
    const float* w2b = (const float*)d_in[14]; const float* g2b = (const float*)d_in[15]; const float* b2b = (const float*)d_in[16];
    const float* w2c = (const float*)d_in[17]; const float* g2c = (const float*)d_in[18]; const float* b2c = (const float*)d_in[19];
    const float* w3a = (const float*)d_in[20]; const float* g3a = (const float*)d_in[21]; const float* b3a = (const float*)d_in[22];
    const float* w3b = (const float*)d_in[23]; const float* g3b = (const float*)d_in[24]; const float* b3b = (const float*)d_in[25];
    const float* w3c = (const float*)d_in[26]; const float* g3c = (const float*)d_in[27]; const float* b3c = (const float*)d_in[28];
    const float* fw1 = (const float*)d_in[29]; const float* fb1 = (const float*)d_in[30];
    const float* fg1 = (const float*)d_in[31]; const float* fbb1 = (const float*)d_in[32];
    const float* fw2 = (const float*)d_in[33]; const float* fb2 = (const float*)d_in[34];
    const float* fg2 = (const float*)d_in[35]; const float* fbb2 = (const float*)d_in[36];
    const float* hw  = (const float*)d_in[37]; const float* hb  = (const float*)d_in[38];
    float* out = (float*)d_out;

    char* ws = (char*)d_ws;
    size_t o = 0;
    auto take = [&](size_t nf) { size_t r = o; o += nf * 4; return r; };
    size_t XYZ  = take(245760);
    size_t CID1 = take(8192);
    size_t NID1 = take(524288);
    size_t NX1  = take(24576);
    size_t CID2 = take(2048);
    size_t NID2 = take(262144);
    size_t NX2  = take(6144);
    size_t FE1  = take(1048576);      // (64,128,128) BN'd SA1 features
    size_t GR3  = take(530432);
    size_t H3A  = take(524288);
    size_t H3B  = take(524288);
    size_t H3C  = take(1048576);
    size_t X3   = take(32768);
    size_t Y1   = take(65536);
    size_t Y2   = take(65536);
    size_t P1X  = take(1048576);
    size_t P1N  = take(1048576);
    size_t WT1H = take(10240);
    size_t WT1L = take(10240);
    size_t WT2H = take(8192);
    size_t WT2L = take(8192);
    size_t WT3H = take(16384);
    size_t WT3L = take(16384);
    size_t WA1H = take(1024);
    size_t WA1L = take(1024);
    size_t WB1H = take(2048);
    size_t WB1L = take(2048);
    size_t WC1H = take(4096);
    size_t WC1L = take(4096);
    size_t Z0   = o;
    size_t STT  = take(11 * 2048);
    size_t MOM  = take(64);
    size_t P2X  = take(524288);
    size_t Z1   = o;
    size_t P2N  = take(524288);
    size_t Z2   = o;
    size_t PSB  = take(2097152);
    size_t PQB  = take(2097152);
    size_t YB   = take(33554432);

    #define Fp(x) ((float*)(ws + (x)))
    #define Ip(x) ((int*)(ws + (x)))
    #define Up(x) ((unsigned*)(ws + (x)))
    #define Hp(x) ((unsigned short*)(ws + (x)))
    auto st = [&](int slot) { return Fp(STT + (size_t)slot * 2048 * 4); };

    hipMemsetAsync(ws + Z0, 0, Z1 - Z0, stream);
    hipMemsetAsync(ws + Z1, 0xFF, Z2 - Z1, stream);

    build_xyz_kernel<<<320, 256, 0, stream>>>(pc, gpc, Fp(XYZ));
    prep_w_kernel<<<328, 256, 0, stream>>>(w2a, w2b, w2c, w1a, w1b, w1c,
        Hp(WT1H), Hp(WT1L), Hp(WT2H), Hp(WT2L), Hp(WT3H), Hp(WT3L),
        Hp(WA1H), Hp(WA1L), Hp(WB1H), Hp(WB1L), Hp(WC1H), Hp(WC1L));

    // ---- SA1 ----
    fps_mw_kernel<5><<<64, 256, 0, stream>>>(Fp(XYZ), 1280, 128, Ip(CID1));
    ball_query_kernel<<<dim3(64, 32), 256, 0, stream>>>(Fp(XYZ), Ip(CID1), 1280, 128, 64,
                                                        (float)(0.02 * 0.02), Ip(NID1), Fp(NX1));
    sa1_moment_kernel<<<256, 256, 0, stream>>>(Fp(XYZ), Ip(NID1), Fp(NX1), Fp(MOM));
    sa1_mom_fin_kernel<<<1, 64, 0, stream>>>(Fp(MOM), w1a, st(0), st(0) + 1024);
    sa1_ab_kernel<<<8192, 256, 0, stream>>>(Fp(XYZ), Ip(NID1), Fp(NX1),
        Hp(WA1H), Hp(WA1L), Hp(WB1H), Hp(WB1L),
        st(0), st(0) + 1024, g1a, b1a, Fp(PSB), Fp(PQB), Fp(YB));
    reduce_stats_kernel<<<dim3(64, 8), 256, 0, stream>>>(Fp(PSB), Fp(PQB), 8192, 64,
        st(1), st(1) + 1024);
    sa1_c_kernel<<<4096, 512, 0, stream>>>(Fp(YB), Hp(WC1H), Hp(WC1L),
        st(1), st(1) + 1024, g1b, b1b, Fp(PSB), Fp(PQB), Fp(P1X), Fp(P1N));
    reduce_stats_kernel<<<dim3(128, 8), 256, 0, stream>>>(Fp(PSB), Fp(PQB), 4096, 128,
        st(2), st(2) + 1024);
    bnpool_fin_kernel<<<4096, 256, 0, stream>>>(Fp(P1X), Fp(P1N), st(2), st(2) + 1024,
                                                g1c, b1c, 1.f / 524288.f, Fp(FE1), 1048576, 127);

    // ---- SA2 ----
    fps_wave_kernel<2><<<64, 64, 0, stream>>>(Fp(NX1), 128, 32, Ip(CID2));
    ball_query_kernel<<<dim3(64, 8), 256, 0, stream>>>(Fp(NX1), Ip(CID2), 128, 32, 128,
                                                       (float)(0.04 * 0.04), Ip(NID2), Fp(NX2));
    sa2_a_kernel<<<4096, 512, 0, stream>>>(Fp(NX1), Ip(NID2), Fp(NX2), Fp(FE1),
        Hp(WT1H), Hp(WT1L), Fp(PSB), Fp(PQB), Fp(YB));
    reduce_stats_kernel<<<dim3(128, 8), 256, 0, stream>>>(Fp(PSB), Fp(PQB), 4096, 128,
        st(3), st(3) + 1024);
    sa2_b_kernel<<<4096, 512, 0, stream>>>(Fp(YB), Hp(WT2H), Hp(WT2L),
        st(3), st(3) + 1024, g2a, b2a, Fp(PSB), Fp(PQB));
    reduce_stats_kernel<<<dim3(128, 8), 256, 0, stream>>>(Fp(PSB), Fp(PQB), 4096, 128,
        st(4), st(4) + 1024);
    sa2_c_kernel<<<4096, 512, 0, stream>>>(Fp(YB), Hp(WT3H), Hp(WT3L),
        st(4), st(4) + 1024, g2b, b2b, Fp(PSB), Fp(PQB), Up(P2X), Up(P2N));
    reduce_stats_kernel<<<dim3(256, 8), 256, 0, stream>>>(Fp(PSB), Fp(PQB), 4096, 256,
        st(5), st(5) + 1024);

    // ---- SA3 ----
    grouped3_prep_kernel<<<2048, 256, 0, stream>>>(Fp(NX2), Up(P2X), Up(P2N),
        st(5), st(5) + 1024, g2c, b2c, 1.f / 262144.f, Fp(GR3));
    gemm_bn_kernel<<<dim3(32, 4), 256, 0, stream>>>(Fp(GR3), w3a, nullptr, Fp(H3A),
        nullptr, nullptr, nullptr, nullptr, 0.f, st(6), st(6) + 1024, 2048, 259, 256);
    gemm_bn_kernel<<<dim3(32, 4), 256, 0, stream>>>(Fp(H3A), w3b, nullptr, Fp(H3B),
        st(6), st(6) + 1024, g3a, b3a, 1.f / 2048.f, st(7), st(7) + 1024, 2048, 256, 256);
    gemm_bn_kernel<<<dim3(32, 8), 256, 0, stream>>>(Fp(H3B), w3c, nullptr, Fp(H3C),
        st(7), st(7) + 1024, g3b, b3b, 1.f / 2048.f, st(8), st(8) + 1024, 2048, 256, 512);
    pool3_kernel<<<128, 256, 0, stream>>>(Fp(H3C), st(8), st(8) + 1024, g3c, b3c, Fp(X3));

    // ---- FC head (split-K, KS=16; col-stats fused into fc_fin) ----
    fc_gemm_kernel<<<dim3(16, 16), 256, 0, stream>>>(Fp(X3), fw1,
        nullptr, nullptr, nullptr, nullptr, 0.f, Fp(PSB), 512, 1024);
    fc_fin_kernel<<<256, 256, 0, stream>>>(Fp(PSB), fb1, 1024, 16, Fp(Y1),
        st(9), st(9) + 1024);
    fc_gemm_kernel<<<dim3(16, 16), 256, 0, stream>>>(Fp(Y1), fw2,
        st(9), st(9) + 1024, fg1, fbb1, 1.f / 64.f, Fp(PSB), 1024, 1024);
    fc_fin_kernel<<<256, 256, 0, stream>>>(Fp(PSB), fb2, 1024, 16, Fp(Y2),
        st(10), st(10) + 1024);
    head_kernel<<<64, 256, 0, stream>>>(Fp(Y2), st(10), st(10) + 1024, fg2, fbb2, hw, hb, out);

    #undef Fp
    #undef Ip
    #undef Up
    #undef Hp
}